// Round 1
// baseline (3069.005 us; speedup 1.0000x reference)
//
#include <hip/hip_runtime.h>
#include <hip/hip_bf16.h>
#include <cstdint>

// Problem constants (LightMutilHeadSelfAttention, PVT-style SR attention)
constexpr int BATCH = 4;
constexpr int CDIM  = 512;        // channels
constexpr int NHEAD = 8;
constexpr int HD    = 64;         // head dim
constexpr int FSP   = 56;         // feature spatial
constexpr int NTOK  = FSP * FSP;  // 3136 query tokens
constexpr int KH    = 28;         // reduced spatial
constexpr int KNTOK = KH * KH;    // 784 kv tokens
constexpr float SCALE_ATT = 0.125f;   // 64^-0.5
constexpr float NEG_BIG = -1e30f;

// ---------------------------------------------------------------------------
// K1: Q projection.  Q[b][n][co] = sum_c x[b][c][n] * Wq[c][co]
// x viewed as A^T (k-major, n contiguous) -> coalesced staging.
// ---------------------------------------------------------------------------
__global__ __launch_bounds__(256) void k_qproj(const float* __restrict__ x,
                                               const float* __restrict__ Wq,
                                               float* __restrict__ Q) {
  __shared__ float As[16][64];
  __shared__ float Bs[16][64];
  const int b  = blockIdx.z;
  const int m0 = blockIdx.x * 64;   // n tile
  const int n0 = blockIdx.y * 64;   // co tile
  const int tid = threadIdx.x;
  const int ty = tid >> 4, tx = tid & 15;
  const float* xb = x + (size_t)b * CDIM * NTOK;
  float acc[4][4] = {};
  for (int k0 = 0; k0 < CDIM; k0 += 16) {
#pragma unroll
    for (int l = 0; l < 4; ++l) {
      const int idx = tid + l * 256;
      const int kk = idx >> 6, mm = idx & 63;
      As[kk][mm] = xb[(size_t)(k0 + kk) * NTOK + m0 + mm];
      Bs[kk][mm] = Wq[(size_t)(k0 + kk) * CDIM + n0 + mm];
    }
    __syncthreads();
#pragma unroll
    for (int kk = 0; kk < 16; ++kk) {
      const float4 av = *(const float4*)&As[kk][ty * 4];
      const float4 bv = *(const float4*)&Bs[kk][tx * 4];
      const float a[4] = {av.x, av.y, av.z, av.w};
      const float bb[4] = {bv.x, bv.y, bv.z, bv.w};
#pragma unroll
      for (int r = 0; r < 4; ++r)
#pragma unroll
        for (int c = 0; c < 4; ++c) acc[r][c] += a[r] * bb[c];
    }
    __syncthreads();
  }
#pragma unroll
  for (int r = 0; r < 4; ++r) {
    float4 v = make_float4(acc[r][0], acc[r][1], acc[r][2], acc[r][3]);
    *(float4*)&Q[((size_t)b * NTOK + m0 + ty * 4 + r) * CDIM + n0 + tx * 4] = v;
  }
}

// ---------------------------------------------------------------------------
// K2a: spatial-reduction conv (2x2 stride-2 VALID) as GEMM.
// XR[b][m][o] = sum_{k=0..2047} patch[m][k] * Wsr_flat[o*2048+k] + b_sr[o]
// with k = c*4 + di*2 + dj, m = i*28+j, patch = x[b][c][2i+di][2j+dj].
// ---------------------------------------------------------------------------
__global__ __launch_bounds__(256) void k_srconv(const float* __restrict__ x,
                                                const float* __restrict__ Wsr,
                                                const float* __restrict__ b_sr,
                                                float* __restrict__ XR) {
  __shared__ float As[16][64];
  __shared__ float Bs[16][64];
  const int b  = blockIdx.z;
  const int m0 = blockIdx.x * 64;   // m tile (784)
  const int n0 = blockIdx.y * 64;   // o tile (512)
  const int tid = threadIdx.x;
  const int ty = tid >> 4, tx = tid & 15;
  const float* xb = x + (size_t)b * CDIM * NTOK;
  // per-thread fixed staging coords
  int pre_kk[4], pre_mm[4], pre_sp[4];
  bool pre_valid[4];
#pragma unroll
  for (int l = 0; l < 4; ++l) {
    const int idx = tid + l * 256;
    const int kk = idx >> 6, mm = idx & 63;
    const int m = m0 + mm;
    pre_kk[l] = kk;
    pre_mm[l] = mm;
    pre_valid[l] = (m < KNTOK);
    const int mc = pre_valid[l] ? m : 0;
    const int i = mc / KH, j = mc % KH;
    pre_sp[l] = (2 * i) * FSP + 2 * j;
  }
  const int bnn = tid >> 2;
  const int bkq = (tid & 3) * 4;
  float acc[4][4] = {};
  for (int k0 = 0; k0 < 2048; k0 += 16) {
#pragma unroll
    for (int l = 0; l < 4; ++l) {
      const int k = k0 + pre_kk[l];
      const int c = k >> 2, di = (k >> 1) & 1, dj = k & 1;
      float v = 0.f;
      if (pre_valid[l]) v = xb[(size_t)c * NTOK + pre_sp[l] + di * FSP + dj];
      As[pre_kk[l]][pre_mm[l]] = v;
    }
    {
      const float4 w = *(const float4*)&Wsr[(size_t)(n0 + bnn) * 2048 + k0 + bkq];
      Bs[bkq + 0][bnn] = w.x;
      Bs[bkq + 1][bnn] = w.y;
      Bs[bkq + 2][bnn] = w.z;
      Bs[bkq + 3][bnn] = w.w;
    }
    __syncthreads();
#pragma unroll
    for (int kk = 0; kk < 16; ++kk) {
      const float4 av = *(const float4*)&As[kk][ty * 4];
      const float4 bv = *(const float4*)&Bs[kk][tx * 4];
      const float a[4] = {av.x, av.y, av.z, av.w};
      const float bb[4] = {bv.x, bv.y, bv.z, bv.w};
#pragma unroll
      for (int r = 0; r < 4; ++r)
#pragma unroll
        for (int c = 0; c < 4; ++c) acc[r][c] += a[r] * bb[c];
    }
    __syncthreads();
  }
  const float4 bias4 = *(const float4*)&b_sr[n0 + tx * 4];
  const float bb[4] = {bias4.x, bias4.y, bias4.z, bias4.w};
#pragma unroll
  for (int r = 0; r < 4; ++r) {
    const int m = m0 + ty * 4 + r;
    if (m < KNTOK) {
      float4 v = make_float4(acc[r][0] + bb[0], acc[r][1] + bb[1],
                             acc[r][2] + bb[2], acc[r][3] + bb[3]);
      *(float4*)&XR[((size_t)b * KNTOK + m) * CDIM + n0 + tx * 4] = v;
    }
  }
}

// ---------------------------------------------------------------------------
// K2b: LayerNorm over the 512 channels of each (b,m) row, in place.
// ---------------------------------------------------------------------------
__global__ __launch_bounds__(256) void k_ln(float* __restrict__ XR,
                                            const float* __restrict__ gamma,
                                            const float* __restrict__ beta) {
  const int row = blockIdx.x;  // b*KNTOK + m
  float* p = XR + (size_t)row * CDIM;
  const int tid = threadIdx.x;
  const float v0 = p[tid], v1 = p[tid + 256];
  float s = v0 + v1;
  float s2 = v0 * v0 + v1 * v1;
#pragma unroll
  for (int mask = 32; mask >= 1; mask >>= 1) {
    s  += __shfl_xor(s, mask, 64);
    s2 += __shfl_xor(s2, mask, 64);
  }
  __shared__ float ws[4], ws2[4];
  const int wid = tid >> 6;
  if ((tid & 63) == 0) { ws[wid] = s; ws2[wid] = s2; }
  __syncthreads();
  const float ts  = ws[0] + ws[1] + ws[2] + ws[3];
  const float ts2 = ws2[0] + ws2[1] + ws2[2] + ws2[3];
  const float mu  = ts * (1.f / CDIM);
  const float var = ts2 * (1.f / CDIM) - mu * mu;
  const float rs  = rsqrtf(var + 1e-5f);
  p[tid]       = (v0 - mu) * rs * gamma[tid] + beta[tid];
  p[tid + 256] = (v1 - mu) * rs * gamma[tid + 256] + beta[tid + 256];
}

// ---------------------------------------------------------------------------
// K2c: KV projection + scatter into K/V (b,h,m,d) layouts.
// kv column o2 in [0,1024): d=o2>>4, h=(o2>>1)&7, w=o2&1 (w=0 -> K, 1 -> V)
// ---------------------------------------------------------------------------
__global__ __launch_bounds__(256) void k_kvproj(const float* __restrict__ XKV,
                                                const float* __restrict__ Wkv,
                                                float* __restrict__ Kk,
                                                float* __restrict__ Vv) {
  __shared__ float As[64][17];
  __shared__ float Bs[16][64];
  const int b  = blockIdx.z;
  const int m0 = blockIdx.x * 64;   // m tile (784)
  const int n0 = blockIdx.y * 64;   // o2 tile (1024)
  const int tid = threadIdx.x;
  const int ty = tid >> 4, tx = tid & 15;
  const int amm = tid >> 2, akq = (tid & 3) * 4;
  const int am = m0 + amm;
  const bool avalid = am < KNTOK;
  float acc[4][4] = {};
  for (int k0 = 0; k0 < CDIM; k0 += 16) {
    {
      float4 av = make_float4(0.f, 0.f, 0.f, 0.f);
      if (avalid) av = *(const float4*)&XKV[((size_t)b * KNTOK + am) * CDIM + k0 + akq];
      As[amm][akq + 0] = av.x;
      As[amm][akq + 1] = av.y;
      As[amm][akq + 2] = av.z;
      As[amm][akq + 3] = av.w;
    }
#pragma unroll
    for (int l = 0; l < 4; ++l) {
      const int idx = tid + l * 256;
      const int kk = idx >> 6, nn = idx & 63;
      Bs[kk][nn] = Wkv[(size_t)(k0 + kk) * 1024 + n0 + nn];
    }
    __syncthreads();
#pragma unroll
    for (int kk = 0; kk < 16; ++kk) {
      const float a[4] = {As[ty * 4 + 0][kk], As[ty * 4 + 1][kk],
                          As[ty * 4 + 2][kk], As[ty * 4 + 3][kk]};
      const float4 bv = *(const float4*)&Bs[kk][tx * 4];
      const float bb[4] = {bv.x, bv.y, bv.z, bv.w};
#pragma unroll
      for (int r = 0; r < 4; ++r)
#pragma unroll
        for (int c = 0; c < 4; ++c) acc[r][c] += a[r] * bb[c];
    }
    __syncthreads();
  }
#pragma unroll
  for (int r = 0; r < 4; ++r) {
    const int m = m0 + ty * 4 + r;
    if (m >= KNTOK) continue;
#pragma unroll
    for (int c = 0; c < 4; ++c) {
      const int o2 = n0 + tx * 4 + c;
      const int d = o2 >> 4;
      const int h = (o2 >> 1) & 7;
      float* dst = (o2 & 1) ? Vv : Kk;
      dst[(((size_t)b * NHEAD + h) * KNTOK + m) * HD + d] = acc[r][c];
    }
  }
}

// ---------------------------------------------------------------------------
// K3: relative-position bias gather -> biasM[n][m], n<3136, m<784.
// ---------------------------------------------------------------------------
__global__ __launch_bounds__(256) void k_bias(const int* __restrict__ rel,
                                              const float* __restrict__ pos,
                                              float* __restrict__ biasM) {
  const int n = blockIdx.x;
  for (int m = threadIdx.x; m < KNTOK; m += 256) {
    const size_t o = ((size_t)n * NTOK + m) * 2;
    biasM[(size_t)n * KNTOK + m] = pos[rel[o] * 111 + rel[o + 1]];
  }
}

// ---------------------------------------------------------------------------
// K4: flash-style attention. Per block: one (b,h), 64 query rows.
// 13 chunks of 64 kv tokens, online softmax, fp32 throughout.
// ---------------------------------------------------------------------------
__global__ __launch_bounds__(256) void k_attn(const float* __restrict__ Q,
                                              const float* __restrict__ Kk,
                                              const float* __restrict__ Vv,
                                              const float* __restrict__ biasM,
                                              float* __restrict__ Og) {
  __shared__ float Qs[64][64];
  __shared__ float Ks[64][64];
  __shared__ float Vs[64][64];
  __shared__ float Ps[64][64];
  const int b = blockIdx.z, h = blockIdx.y;
  const int n0 = blockIdx.x * 64;
  const int tid = threadIdx.x;
  const int ty = tid >> 4, tx = tid & 15;
  const float* qbase = Q + ((size_t)b * NTOK + n0) * CDIM + h * HD;
  const float* kbase = Kk + ((size_t)b * NHEAD + h) * KNTOK * HD;
  const float* vbase = Vv + ((size_t)b * NHEAD + h) * KNTOK * HD;
#pragma unroll
  for (int l = 0; l < 4; ++l) {
    const int idx4 = tid + l * 256;
    const int row = idx4 >> 4, col4 = (idx4 & 15) * 4;
    *(float4*)&Qs[row][col4] = *(const float4*)&qbase[(size_t)row * CDIM + col4];
  }
  float acc[4][4] = {};
  float m_run[4] = {NEG_BIG, NEG_BIG, NEG_BIG, NEG_BIG};
  float l_run[4] = {};
  __syncthreads();
  for (int jc = 0; jc < 13; ++jc) {
    const int mb = jc * 64;
#pragma unroll
    for (int l = 0; l < 4; ++l) {
      const int idx4 = tid + l * 256;
      const int row = idx4 >> 4, col4 = (idx4 & 15) * 4;
      const int m = mb + row;
      float4 kv = make_float4(0.f, 0.f, 0.f, 0.f);
      float4 vv = make_float4(0.f, 0.f, 0.f, 0.f);
      if (m < KNTOK) {
        kv = *(const float4*)&kbase[(size_t)m * HD + col4];
        vv = *(const float4*)&vbase[(size_t)m * HD + col4];
      }
      *(float4*)&Ks[row][col4] = kv;
      *(float4*)&Vs[row][col4] = vv;
    }
    __syncthreads();
    // S = Q K^T for this chunk
    float s[4][4] = {};
#pragma unroll
    for (int d0 = 0; d0 < 64; d0 += 4) {
      float4 qv[4], kv[4];
#pragma unroll
      for (int r = 0; r < 4; ++r) qv[r] = *(const float4*)&Qs[ty * 4 + r][d0];
#pragma unroll
      for (int c = 0; c < 4; ++c) kv[c] = *(const float4*)&Ks[tx * 4 + c][d0];
#pragma unroll
      for (int r = 0; r < 4; ++r)
#pragma unroll
        for (int c = 0; c < 4; ++c)
          s[r][c] += qv[r].x * kv[c].x + qv[r].y * kv[c].y +
                     qv[r].z * kv[c].z + qv[r].w * kv[c].w;
    }
    // scale + bias + validity
#pragma unroll
    for (int r = 0; r < 4; ++r) {
      const float* brow = biasM + (size_t)(n0 + ty * 4 + r) * KNTOK;
#pragma unroll
      for (int c = 0; c < 4; ++c) {
        const int m = mb + tx * 4 + c;
        s[r][c] = (m < KNTOK) ? (s[r][c] * SCALE_ATT + brow[m]) : NEG_BIG;
      }
    }
    // online softmax update (row stats across 16 tx-lanes)
#pragma unroll
    for (int r = 0; r < 4; ++r) {
      float mx = fmaxf(fmaxf(s[r][0], s[r][1]), fmaxf(s[r][2], s[r][3]));
#pragma unroll
      for (int mask = 1; mask < 16; mask <<= 1) mx = fmaxf(mx, __shfl_xor(mx, mask, 64));
      const float mnew = fmaxf(m_run[r], mx);
      const float alpha = __expf(m_run[r] - mnew);
      float lsum = 0.f;
#pragma unroll
      for (int c = 0; c < 4; ++c) {
        const float pv = __expf(s[r][c] - mnew);
        s[r][c] = pv;
        lsum += pv;
      }
#pragma unroll
      for (int mask = 1; mask < 16; mask <<= 1) lsum += __shfl_xor(lsum, mask, 64);
      l_run[r] = l_run[r] * alpha + lsum;
      m_run[r] = mnew;
#pragma unroll
      for (int c = 0; c < 4; ++c) acc[r][c] *= alpha;
    }
#pragma unroll
    for (int r = 0; r < 4; ++r)
#pragma unroll
      for (int c = 0; c < 4; ++c) Ps[ty * 4 + r][tx * 4 + c] = s[r][c];
    __syncthreads();
    // O += P V
#pragma unroll
    for (int k0 = 0; k0 < 64; k0 += 4) {
      float4 pv[4], vv[4];
#pragma unroll
      for (int r = 0; r < 4; ++r) pv[r] = *(const float4*)&Ps[ty * 4 + r][k0];
#pragma unroll
      for (int kk = 0; kk < 4; ++kk) vv[kk] = *(const float4*)&Vs[k0 + kk][tx * 4];
#pragma unroll
      for (int r = 0; r < 4; ++r) {
        const float pf[4] = {pv[r].x, pv[r].y, pv[r].z, pv[r].w};
        acc[r][0] += pf[0] * vv[0].x + pf[1] * vv[1].x + pf[2] * vv[2].x + pf[3] * vv[3].x;
        acc[r][1] += pf[0] * vv[0].y + pf[1] * vv[1].y + pf[2] * vv[2].y + pf[3] * vv[3].y;
        acc[r][2] += pf[0] * vv[0].z + pf[1] * vv[1].z + pf[2] * vv[2].z + pf[3] * vv[3].z;
        acc[r][3] += pf[0] * vv[0].w + pf[1] * vv[1].w + pf[2] * vv[2].w + pf[3] * vv[3].w;
      }
    }
    __syncthreads();
  }
#pragma unroll
  for (int r = 0; r < 4; ++r) {
    const float inv = 1.f / l_run[r];
    float4 o = make_float4(acc[r][0] * inv, acc[r][1] * inv,
                           acc[r][2] * inv, acc[r][3] * inv);
    *(float4*)&Og[((size_t)b * NTOK + n0 + ty * 4 + r) * CDIM + h * HD + tx * 4] = o;
  }
}

// ---------------------------------------------------------------------------
// K5: output projection + bp, store transposed to (b, co, n).
// ---------------------------------------------------------------------------
__global__ __launch_bounds__(256) void k_outproj(const float* __restrict__ Og,
                                                 const float* __restrict__ Wp,
                                                 const float* __restrict__ bp,
                                                 float* __restrict__ out) {
  __shared__ float As[64][17];
  __shared__ float Bs[16][64];
  const int b  = blockIdx.z;
  const int m0 = blockIdx.x * 64;   // n tile
  const int n0 = blockIdx.y * 64;   // co tile
  const int tid = threadIdx.x;
  const int ty = tid >> 4, tx = tid & 15;
  const int amm = tid >> 2, akq = (tid & 3) * 4;
  float acc[4][4] = {};
  for (int k0 = 0; k0 < CDIM; k0 += 16) {
    {
      const float4 av = *(const float4*)&Og[((size_t)b * NTOK + m0 + amm) * CDIM + k0 + akq];
      As[amm][akq + 0] = av.x;
      As[amm][akq + 1] = av.y;
      As[amm][akq + 2] = av.z;
      As[amm][akq + 3] = av.w;
    }
#pragma unroll
    for (int l = 0; l < 4; ++l) {
      const int idx = tid + l * 256;
      const int kk = idx >> 6, nn = idx & 63;
      Bs[kk][nn] = Wp[(size_t)(k0 + kk) * CDIM + n0 + nn];
    }
    __syncthreads();
#pragma unroll
    for (int kk = 0; kk < 16; ++kk) {
      const float a[4] = {As[ty * 4 + 0][kk], As[ty * 4 + 1][kk],
                          As[ty * 4 + 2][kk], As[ty * 4 + 3][kk]};
      const float4 bv = *(const float4*)&Bs[kk][tx * 4];
      const float bb[4] = {bv.x, bv.y, bv.z, bv.w};
#pragma unroll
      for (int r = 0; r < 4; ++r)
#pragma unroll
        for (int c = 0; c < 4; ++c) acc[r][c] += a[r] * bb[c];
    }
    __syncthreads();
  }
#pragma unroll
  for (int c = 0; c < 4; ++c) {
    const int co = n0 + tx * 4 + c;
    const float bpv = bp[co];
    float4 v = make_float4(acc[0][c] + bpv, acc[1][c] + bpv,
                           acc[2][c] + bpv, acc[3][c] + bpv);
    *(float4*)&out[((size_t)b * CDIM + co) * NTOK + m0 + ty * 4] = v;
  }
}

// ---------------------------------------------------------------------------
extern "C" void kernel_launch(void* const* d_in, const int* in_sizes, int n_in,
                              void* d_out, int out_size, void* d_ws, size_t ws_size,
                              hipStream_t stream) {
  const float* x     = (const float*)d_in[0];
  const float* Wq    = (const float*)d_in[1];
  const float* Wkv   = (const float*)d_in[2];
  const float* Wsr   = (const float*)d_in[3];
  const float* b_sr  = (const float*)d_in[4];
  const float* gamma = (const float*)d_in[5];
  const float* beta  = (const float*)d_in[6];
  const float* Wp    = (const float*)d_in[7];
  const float* bp    = (const float*)d_in[8];
  const float* pos   = (const float*)d_in[9];
  const int*   rel   = (const int*)d_in[10];
  float* out = (float*)d_out;

  // workspace carve-up (floats): total ~20.1M floats = 80.5 MB
  float* ws    = (float*)d_ws;
  float* Qb    = ws;                                      // 4*3136*512
  float* XR    = Qb + (size_t)BATCH * NTOK * CDIM;        // 4*784*512
  float* Kk    = XR + (size_t)BATCH * KNTOK * CDIM;       // 4*8*784*64
  float* Vv    = Kk + (size_t)BATCH * NHEAD * KNTOK * HD; // 4*8*784*64
  float* biasM = Vv + (size_t)BATCH * NHEAD * KNTOK * HD; // 3136*784
  float* Og    = biasM + (size_t)NTOK * KNTOK;            // 4*3136*512

  const dim3 blk(256);
  k_qproj  <<<dim3(NTOK / 64, CDIM / 64, BATCH), blk, 0, stream>>>(x, Wq, Qb);
  k_srconv <<<dim3(13, CDIM / 64, BATCH),        blk, 0, stream>>>(x, Wsr, b_sr, XR);
  k_ln     <<<dim3(BATCH * KNTOK),               blk, 0, stream>>>(XR, gamma, beta);
  k_kvproj <<<dim3(13, 1024 / 64, BATCH),        blk, 0, stream>>>(XR, Wkv, Kk, Vv);
  k_bias   <<<dim3(NTOK),                        blk, 0, stream>>>(rel, pos, biasM);
  k_attn   <<<dim3(NTOK / 64, NHEAD, BATCH),     blk, 0, stream>>>(Qb, Kk, Vv, biasM, Og);
  k_outproj<<<dim3(NTOK / 64, CDIM / 64, BATCH), blk, 0, stream>>>(Og, Wp, bp, out);
}

// Round 2
// 936.557 us; speedup vs baseline: 3.2769x; 3.2769x over previous
//
#include <hip/hip_runtime.h>
#include <hip/hip_bf16.h>
#include <cstdint>

// Problem constants (LightMutilHeadSelfAttention, PVT-style SR attention)
constexpr int BATCH = 4;
constexpr int CDIM  = 512;        // channels
constexpr int NHEAD = 8;
constexpr int HD    = 64;         // head dim
constexpr int FSP   = 56;         // feature spatial
constexpr int NTOK  = FSP * FSP;  // 3136 query tokens
constexpr int KH    = 28;         // reduced spatial
constexpr int KNTOK = KH * KH;    // 784 kv tokens
constexpr float SCALE_ATT = 0.125f;   // 64^-0.5
constexpr float NEG_BIG = -1e30f;

typedef __attribute__((ext_vector_type(8))) short  short8;
typedef __attribute__((ext_vector_type(4))) float  floatx4;

// round-to-nearest-even fp32 -> bf16 (bit pattern)
__device__ __forceinline__ unsigned short f2bf(float f) {
  union { float f; uint32_t u; } v; v.f = f;
  uint32_t u = v.u;
  return (unsigned short)((u + 0x7fffu + ((u >> 16) & 1u)) >> 16);
}
__device__ __forceinline__ float bf2f(unsigned short h) {
  union { uint32_t u; float f; } v; v.u = ((uint32_t)h) << 16;
  return v.f;
}

// ---------------------------------------------------------------------------
// K1: Q projection.  Q[b][n][co] = sum_c x[b][c][n] * Wq[c][co]
// ---------------------------------------------------------------------------
__global__ __launch_bounds__(256) void k_qproj(const float* __restrict__ x,
                                               const float* __restrict__ Wq,
                                               float* __restrict__ Q) {
  __shared__ float As[16][64];
  __shared__ float Bs[16][64];
  const int b  = blockIdx.z;
  const int m0 = blockIdx.x * 64;   // n tile
  const int n0 = blockIdx.y * 64;   // co tile
  const int tid = threadIdx.x;
  const int ty = tid >> 4, tx = tid & 15;
  const float* xb = x + (size_t)b * CDIM * NTOK;
  float acc[4][4] = {};
  for (int k0 = 0; k0 < CDIM; k0 += 16) {
#pragma unroll
    for (int l = 0; l < 4; ++l) {
      const int idx = tid + l * 256;
      const int kk = idx >> 6, mm = idx & 63;
      As[kk][mm] = xb[(size_t)(k0 + kk) * NTOK + m0 + mm];
      Bs[kk][mm] = Wq[(size_t)(k0 + kk) * CDIM + n0 + mm];
    }
    __syncthreads();
#pragma unroll
    for (int kk = 0; kk < 16; ++kk) {
      const float4 av = *(const float4*)&As[kk][ty * 4];
      const float4 bv = *(const float4*)&Bs[kk][tx * 4];
      const float a[4] = {av.x, av.y, av.z, av.w};
      const float bb[4] = {bv.x, bv.y, bv.z, bv.w};
#pragma unroll
      for (int r = 0; r < 4; ++r)
#pragma unroll
        for (int c = 0; c < 4; ++c) acc[r][c] += a[r] * bb[c];
    }
    __syncthreads();
  }
#pragma unroll
  for (int r = 0; r < 4; ++r) {
    float4 v = make_float4(acc[r][0], acc[r][1], acc[r][2], acc[r][3]);
    *(float4*)&Q[((size_t)b * NTOK + m0 + ty * 4 + r) * CDIM + n0 + tx * 4] = v;
  }
}

// ---------------------------------------------------------------------------
// K2a: spatial-reduction conv (2x2 stride-2 VALID) as GEMM.
// ---------------------------------------------------------------------------
__global__ __launch_bounds__(256) void k_srconv(const float* __restrict__ x,
                                                const float* __restrict__ Wsr,
                                                const float* __restrict__ b_sr,
                                                float* __restrict__ XR) {
  __shared__ float As[16][64];
  __shared__ float Bs[16][64];
  const int b  = blockIdx.z;
  const int m0 = blockIdx.x * 64;   // m tile (784)
  const int n0 = blockIdx.y * 64;   // o tile (512)
  const int tid = threadIdx.x;
  const int ty = tid >> 4, tx = tid & 15;
  const float* xb = x + (size_t)b * CDIM * NTOK;
  int pre_kk[4], pre_mm[4], pre_sp[4];
  bool pre_valid[4];
#pragma unroll
  for (int l = 0; l < 4; ++l) {
    const int idx = tid + l * 256;
    const int kk = idx >> 6, mm = idx & 63;
    const int m = m0 + mm;
    pre_kk[l] = kk;
    pre_mm[l] = mm;
    pre_valid[l] = (m < KNTOK);
    const int mc = pre_valid[l] ? m : 0;
    const int i = mc / KH, j = mc % KH;
    pre_sp[l] = (2 * i) * FSP + 2 * j;
  }
  const int bnn = tid >> 2;
  const int bkq = (tid & 3) * 4;
  float acc[4][4] = {};
  for (int k0 = 0; k0 < 2048; k0 += 16) {
#pragma unroll
    for (int l = 0; l < 4; ++l) {
      const int k = k0 + pre_kk[l];
      const int c = k >> 2, di = (k >> 1) & 1, dj = k & 1;
      float v = 0.f;
      if (pre_valid[l]) v = xb[(size_t)c * NTOK + pre_sp[l] + di * FSP + dj];
      As[pre_kk[l]][pre_mm[l]] = v;
    }
    {
      const float4 w = *(const float4*)&Wsr[(size_t)(n0 + bnn) * 2048 + k0 + bkq];
      Bs[bkq + 0][bnn] = w.x;
      Bs[bkq + 1][bnn] = w.y;
      Bs[bkq + 2][bnn] = w.z;
      Bs[bkq + 3][bnn] = w.w;
    }
    __syncthreads();
#pragma unroll
    for (int kk = 0; kk < 16; ++kk) {
      const float4 av = *(const float4*)&As[kk][ty * 4];
      const float4 bv = *(const float4*)&Bs[kk][tx * 4];
      const float a[4] = {av.x, av.y, av.z, av.w};
      const float bb[4] = {bv.x, bv.y, bv.z, bv.w};
#pragma unroll
      for (int r = 0; r < 4; ++r)
#pragma unroll
        for (int c = 0; c < 4; ++c) acc[r][c] += a[r] * bb[c];
    }
    __syncthreads();
  }
  const float4 bias4 = *(const float4*)&b_sr[n0 + tx * 4];
  const float bb[4] = {bias4.x, bias4.y, bias4.z, bias4.w};
#pragma unroll
  for (int r = 0; r < 4; ++r) {
    const int m = m0 + ty * 4 + r;
    if (m < KNTOK) {
      float4 v = make_float4(acc[r][0] + bb[0], acc[r][1] + bb[1],
                             acc[r][2] + bb[2], acc[r][3] + bb[3]);
      *(float4*)&XR[((size_t)b * KNTOK + m) * CDIM + n0 + tx * 4] = v;
    }
  }
}

// ---------------------------------------------------------------------------
// K2b: LayerNorm over the 512 channels of each (b,m) row, in place.
// ---------------------------------------------------------------------------
__global__ __launch_bounds__(256) void k_ln(float* __restrict__ XR,
                                            const float* __restrict__ gamma,
                                            const float* __restrict__ beta) {
  const int row = blockIdx.x;  // b*KNTOK + m
  float* p = XR + (size_t)row * CDIM;
  const int tid = threadIdx.x;
  const float v0 = p[tid], v1 = p[tid + 256];
  float s = v0 + v1;
  float s2 = v0 * v0 + v1 * v1;
#pragma unroll
  for (int mask = 32; mask >= 1; mask >>= 1) {
    s  += __shfl_xor(s, mask, 64);
    s2 += __shfl_xor(s2, mask, 64);
  }
  __shared__ float ws[4], ws2[4];
  const int wid = tid >> 6;
  if ((tid & 63) == 0) { ws[wid] = s; ws2[wid] = s2; }
  __syncthreads();
  const float ts  = ws[0] + ws[1] + ws[2] + ws[3];
  const float ts2 = ws2[0] + ws2[1] + ws2[2] + ws2[3];
  const float mu  = ts * (1.f / CDIM);
  const float var = ts2 * (1.f / CDIM) - mu * mu;
  const float rs  = rsqrtf(var + 1e-5f);
  p[tid]       = (v0 - mu) * rs * gamma[tid] + beta[tid];
  p[tid + 256] = (v1 - mu) * rs * gamma[tid + 256] + beta[tid + 256];
}

// ---------------------------------------------------------------------------
// K2c: KV projection + scatter into K/V (b,h,m,d) layouts.
// ---------------------------------------------------------------------------
__global__ __launch_bounds__(256) void k_kvproj(const float* __restrict__ XKV,
                                                const float* __restrict__ Wkv,
                                                float* __restrict__ Kk,
                                                float* __restrict__ Vv) {
  __shared__ float As[64][17];
  __shared__ float Bs[16][64];
  const int b  = blockIdx.z;
  const int m0 = blockIdx.x * 64;   // m tile (784)
  const int n0 = blockIdx.y * 64;   // o2 tile (1024)
  const int tid = threadIdx.x;
  const int ty = tid >> 4, tx = tid & 15;
  const int amm = tid >> 2, akq = (tid & 3) * 4;
  const int am = m0 + amm;
  const bool avalid = am < KNTOK;
  float acc[4][4] = {};
  for (int k0 = 0; k0 < CDIM; k0 += 16) {
    {
      float4 av = make_float4(0.f, 0.f, 0.f, 0.f);
      if (avalid) av = *(const float4*)&XKV[((size_t)b * KNTOK + am) * CDIM + k0 + akq];
      As[amm][akq + 0] = av.x;
      As[amm][akq + 1] = av.y;
      As[amm][akq + 2] = av.z;
      As[amm][akq + 3] = av.w;
    }
#pragma unroll
    for (int l = 0; l < 4; ++l) {
      const int idx = tid + l * 256;
      const int kk = idx >> 6, nn = idx & 63;
      Bs[kk][nn] = Wkv[(size_t)(k0 + kk) * 1024 + n0 + nn];
    }
    __syncthreads();
#pragma unroll
    for (int kk = 0; kk < 16; ++kk) {
      const float a[4] = {As[ty * 4 + 0][kk], As[ty * 4 + 1][kk],
                          As[ty * 4 + 2][kk], As[ty * 4 + 3][kk]};
      const float4 bv = *(const float4*)&Bs[kk][tx * 4];
      const float bb[4] = {bv.x, bv.y, bv.z, bv.w};
#pragma unroll
      for (int r = 0; r < 4; ++r)
#pragma unroll
        for (int c = 0; c < 4; ++c) acc[r][c] += a[r] * bb[c];
    }
    __syncthreads();
  }
#pragma unroll
  for (int r = 0; r < 4; ++r) {
    const int m = m0 + ty * 4 + r;
    if (m >= KNTOK) continue;
#pragma unroll
    for (int c = 0; c < 4; ++c) {
      const int o2 = n0 + tx * 4 + c;
      const int d = o2 >> 4;
      const int h = (o2 >> 1) & 7;
      float* dst = (o2 & 1) ? Vv : Kk;
      dst[(((size_t)b * NHEAD + h) * KNTOK + m) * HD + d] = acc[r][c];
    }
  }
}

// ---------------------------------------------------------------------------
// K3: relative-position bias gather -> biasM[n][m], n<3136, m<784.
// ---------------------------------------------------------------------------
__global__ __launch_bounds__(256) void k_bias(const int* __restrict__ rel,
                                              const float* __restrict__ pos,
                                              float* __restrict__ biasM) {
  const int n = blockIdx.x;
  for (int m = threadIdx.x; m < KNTOK; m += 256) {
    const size_t o = ((size_t)n * NTOK + m) * 2;
    biasM[(size_t)n * KNTOK + m] = pos[rel[o] * 111 + rel[o + 1]];
  }
}

// ---------------------------------------------------------------------------
// K4: MFMA flash attention. Block = (b, h, 64-row q tile); 4 waves; each
// wave owns a 16-row strip. QK^T with bf16 2-term split (3 MFMAs) for
// ~fp32 accuracy; PV in plain bf16 (softmax weights sum to 1 -> tiny err).
// LDS tiles padded to stride 72 (144B rows, 16B aligned) for bank spread.
// ---------------------------------------------------------------------------
#define LSTR 72
__global__ __launch_bounds__(256) void k_attn(const float* __restrict__ Q,
                                              const float* __restrict__ Kk,
                                              const float* __restrict__ Vv,
                                              const float* __restrict__ biasM,
                                              float* __restrict__ Og) {
  __shared__ unsigned short Qhi[64][LSTR];
  __shared__ unsigned short Qlo[64][LSTR];
  __shared__ unsigned short Khi[64][LSTR];
  __shared__ unsigned short Klo[64][LSTR];
  __shared__ unsigned short Vt [64][LSTR];     // V transposed: [dv][mkv]
  __shared__ unsigned short Ps [4][16][LSTR];  // per-wave P strip

  const int b = blockIdx.z, h = blockIdx.y;
  const int n0 = blockIdx.x * 64;
  const int tid = threadIdx.x;
  const int lane = tid & 63, wv = tid >> 6;
  const int quad = lane >> 4, tx = lane & 15;

  const float* qbase = Q + ((size_t)b * NTOK + n0) * CDIM + h * HD;
  const float* kbase = Kk + ((size_t)b * NHEAD + h) * KNTOK * HD;
  const float* vbase = Vv + ((size_t)b * NHEAD + h) * KNTOK * HD;

  // ---- stage Q (64 x 64), split into hi/lo bf16 ----
  {
    const int row = tid >> 2, seg = (tid & 3) * 16;
    const float* src = qbase + (size_t)row * CDIM + seg;
    short8 h0, h1, l0, l1;
#pragma unroll
    for (int j = 0; j < 8; ++j) {
      const float f = src[j];
      const unsigned short hi = f2bf(f);
      h0[j] = (short)hi;
      l0[j] = (short)f2bf(f - bf2f(hi));
    }
#pragma unroll
    for (int j = 0; j < 8; ++j) {
      const float f = src[8 + j];
      const unsigned short hi = f2bf(f);
      h1[j] = (short)hi;
      l1[j] = (short)f2bf(f - bf2f(hi));
    }
    *(short8*)&Qhi[row][seg]     = h0;
    *(short8*)&Qhi[row][seg + 8] = h1;
    *(short8*)&Qlo[row][seg]     = l0;
    *(short8*)&Qlo[row][seg + 8] = l1;
  }

  floatx4 acc_o[4];
#pragma unroll
  for (int t = 0; t < 4; ++t) acc_o[t] = (floatx4){0.f, 0.f, 0.f, 0.f};
  float m_run[4] = {NEG_BIG, NEG_BIG, NEG_BIG, NEG_BIG};
  float l_run[4] = {0.f, 0.f, 0.f, 0.f};

  __syncthreads();

  for (int jc = 0; jc < 13; ++jc) {
    const int mb = jc * 64;
    // ---- stage K chunk (hi/lo) ----
    {
      const int row = tid >> 2, seg = (tid & 3) * 16;
      const int m = mb + row;
      const bool valid = m < KNTOK;
      const float* src = kbase + (size_t)m * HD + seg;
      short8 h0, h1, l0, l1;
#pragma unroll
      for (int j = 0; j < 8; ++j) {
        const float f = valid ? src[j] : 0.f;
        const unsigned short hi = f2bf(f);
        h0[j] = (short)hi;
        l0[j] = (short)f2bf(f - bf2f(hi));
      }
#pragma unroll
      for (int j = 0; j < 8; ++j) {
        const float f = valid ? src[8 + j] : 0.f;
        const unsigned short hi = f2bf(f);
        h1[j] = (short)hi;
        l1[j] = (short)f2bf(f - bf2f(hi));
      }
      *(short8*)&Khi[row][seg]     = h0;
      *(short8*)&Khi[row][seg + 8] = h1;
      *(short8*)&Klo[row][seg]     = l0;
      *(short8*)&Klo[row][seg + 8] = l1;
    }
    // ---- stage V chunk transposed ----
    {
      const int mkv = tid & 63, dvs = (tid >> 6) * 16;
      const int m = mb + mkv;
      const bool valid = m < KNTOK;
      const float* src = vbase + (size_t)m * HD + dvs;
#pragma unroll
      for (int j = 0; j < 16; ++j) {
        const float f = valid ? src[j] : 0.f;
        Vt[dvs + j][mkv] = f2bf(f);
      }
    }
    __syncthreads();

    // ---- S = Q K^T (split bf16: hi*hi + hi*lo + lo*hi) ----
    floatx4 sc[4];
#pragma unroll
    for (int t = 0; t < 4; ++t) sc[t] = (floatx4){0.f, 0.f, 0.f, 0.f};
#pragma unroll
    for (int ks = 0; ks < 2; ++ks) {
      const int k0 = ks * 32 + quad * 8;
      const short8 aqh = *(const short8*)&Qhi[wv * 16 + tx][k0];
      const short8 aql = *(const short8*)&Qlo[wv * 16 + tx][k0];
#pragma unroll
      for (int t = 0; t < 4; ++t) {
        const short8 bkh = *(const short8*)&Khi[t * 16 + tx][k0];
        const short8 bkl = *(const short8*)&Klo[t * 16 + tx][k0];
        sc[t] = __builtin_amdgcn_mfma_f32_16x16x32_bf16(aqh, bkh, sc[t], 0, 0, 0);
        sc[t] = __builtin_amdgcn_mfma_f32_16x16x32_bf16(aqh, bkl, sc[t], 0, 0, 0);
        sc[t] = __builtin_amdgcn_mfma_f32_16x16x32_bf16(aql, bkh, sc[t], 0, 0, 0);
      }
    }

    // ---- scale + bias + online softmax (rows = quad*4+r of wave strip) ----
#pragma unroll
    for (int r = 0; r < 4; ++r) {
      const int grow = n0 + wv * 16 + quad * 4 + r;
      const float* brow = biasM + (size_t)grow * KNTOK;
      float sv[4];
#pragma unroll
      for (int t = 0; t < 4; ++t) {
        const int col = mb + t * 16 + tx;
        sv[t] = (col < KNTOK) ? (sc[t][r] * SCALE_ATT + brow[col]) : NEG_BIG;
      }
      float mx = fmaxf(fmaxf(sv[0], sv[1]), fmaxf(sv[2], sv[3]));
#pragma unroll
      for (int msk = 1; msk < 16; msk <<= 1) mx = fmaxf(mx, __shfl_xor(mx, msk, 64));
      const float mnew = fmaxf(m_run[r], mx);
      const float alpha = __expf(m_run[r] - mnew);
      float lsum = 0.f;
#pragma unroll
      for (int t = 0; t < 4; ++t) {
        const float pv = __expf(sv[t] - mnew);
        lsum += pv;
        Ps[wv][quad * 4 + r][t * 16 + tx] = f2bf(pv);
      }
#pragma unroll
      for (int msk = 1; msk < 16; msk <<= 1) lsum += __shfl_xor(lsum, msk, 64);
      l_run[r] = l_run[r] * alpha + lsum;
      m_run[r] = mnew;
#pragma unroll
      for (int t = 0; t < 4; ++t) acc_o[t][r] *= alpha;
    }

    // ---- O += P V (plain bf16) ----
#pragma unroll
    for (int ks = 0; ks < 2; ++ks) {
      const int k0 = ks * 32 + quad * 8;
      const short8 ap = *(const short8*)&Ps[wv][tx][k0];
#pragma unroll
      for (int t = 0; t < 4; ++t) {
        const short8 bv = *(const short8*)&Vt[t * 16 + tx][k0];
        acc_o[t] = __builtin_amdgcn_mfma_f32_16x16x32_bf16(ap, bv, acc_o[t], 0, 0, 0);
      }
    }
    __syncthreads();
  }

  // ---- epilogue: normalize and store ----
#pragma unroll
  for (int r = 0; r < 4; ++r) {
    const float inv = 1.f / l_run[r];
    const int grow = n0 + wv * 16 + quad * 4 + r;
#pragma unroll
    for (int t = 0; t < 4; ++t) {
      Og[((size_t)b * NTOK + grow) * CDIM + h * HD + t * 16 + tx] = acc_o[t][r] * inv;
    }
  }
}

// ---------------------------------------------------------------------------
// K5: output projection + bp, store transposed to (b, co, n).
// ---------------------------------------------------------------------------
__global__ __launch_bounds__(256) void k_outproj(const float* __restrict__ Og,
                                                 const float* __restrict__ Wp,
                                                 const float* __restrict__ bp,
                                                 float* __restrict__ out) {
  __shared__ float As[64][17];
  __shared__ float Bs[16][64];
  const int b  = blockIdx.z;
  const int m0 = blockIdx.x * 64;   // n tile
  const int n0 = blockIdx.y * 64;   // co tile
  const int tid = threadIdx.x;
  const int ty = tid >> 4, tx = tid & 15;
  const int amm = tid >> 2, akq = (tid & 3) * 4;
  float acc[4][4] = {};
  for (int k0 = 0; k0 < CDIM; k0 += 16) {
    {
      const float4 av = *(const float4*)&Og[((size_t)b * NTOK + m0 + amm) * CDIM + k0 + akq];
      As[amm][akq + 0] = av.x;
      As[amm][akq + 1] = av.y;
      As[amm][akq + 2] = av.z;
      As[amm][akq + 3] = av.w;
    }
#pragma unroll
    for (int l = 0; l < 4; ++l) {
      const int idx = tid + l * 256;
      const int kk = idx >> 6, nn = idx & 63;
      Bs[kk][nn] = Wp[(size_t)(k0 + kk) * CDIM + n0 + nn];
    }
    __syncthreads();
#pragma unroll
    for (int kk = 0; kk < 16; ++kk) {
      const float a[4] = {As[ty * 4 + 0][kk], As[ty * 4 + 1][kk],
                          As[ty * 4 + 2][kk], As[ty * 4 + 3][kk]};
      const float4 bv = *(const float4*)&Bs[kk][tx * 4];
      const float bb[4] = {bv.x, bv.y, bv.z, bv.w};
#pragma unroll
      for (int r = 0; r < 4; ++r)
#pragma unroll
        for (int c = 0; c < 4; ++c) acc[r][c] += a[r] * bb[c];
    }
    __syncthreads();
  }
#pragma unroll
  for (int c = 0; c < 4; ++c) {
    const int co = n0 + tx * 4 + c;
    const float bpv = bp[co];
    float4 v = make_float4(acc[0][c] + bpv, acc[1][c] + bpv,
                           acc[2][c] + bpv, acc[3][c] + bpv);
    *(float4*)&out[((size_t)b * CDIM + co) * NTOK + m0 + ty * 4] = v;
  }
}

// ---------------------------------------------------------------------------
extern "C" void kernel_launch(void* const* d_in, const int* in_sizes, int n_in,
                              void* d_out, int out_size, void* d_ws, size_t ws_size,
                              hipStream_t stream) {
  const float* x     = (const float*)d_in[0];
  const float* Wq    = (const float*)d_in[1];
  const float* Wkv   = (const float*)d_in[2];
  const float* Wsr   = (const float*)d_in[3];
  const float* b_sr  = (const float*)d_in[4];
  const float* gamma = (const float*)d_in[5];
  const float* beta  = (const float*)d_in[6];
  const float* Wp    = (const float*)d_in[7];
  const float* bp    = (const float*)d_in[8];
  const float* pos   = (const float*)d_in[9];
  const int*   rel   = (const int*)d_in[10];
  float* out = (float*)d_out;

  float* ws    = (float*)d_ws;
  float* Qb    = ws;                                      // 4*3136*512
  float* XR    = Qb + (size_t)BATCH * NTOK * CDIM;        // 4*784*512
  float* Kk    = XR + (size_t)BATCH * KNTOK * CDIM;       // 4*8*784*64
  float* Vv    = Kk + (size_t)BATCH * NHEAD * KNTOK * HD; // 4*8*784*64
  float* biasM = Vv + (size_t)BATCH * NHEAD * KNTOK * HD; // 3136*784
  float* Og    = biasM + (size_t)NTOK * KNTOK;            // 4*3136*512

  const dim3 blk(256);
  k_qproj  <<<dim3(NTOK / 64, CDIM / 64, BATCH), blk, 0, stream>>>(x, Wq, Qb);
  k_srconv <<<dim3(13, CDIM / 64, BATCH),        blk, 0, stream>>>(x, Wsr, b_sr, XR);
  k_ln     <<<dim3(BATCH * KNTOK),               blk, 0, stream>>>(XR, gamma, beta);
  k_kvproj <<<dim3(13, 1024 / 64, BATCH),        blk, 0, stream>>>(XR, Wkv, Kk, Vv);
  k_bias   <<<dim3(NTOK),                        blk, 0, stream>>>(rel, pos, biasM);
  k_attn   <<<dim3(NTOK / 64, NHEAD, BATCH),     blk, 0, stream>>>(Qb, Kk, Vv, biasM, Og);
  k_outproj<<<dim3(NTOK / 64, CDIM / 64, BATCH), blk, 0, stream>>>(Og, Wp, bp, out);
}

// Round 3
// 512.315 us; speedup vs baseline: 5.9905x; 1.8281x over previous
//
#include <hip/hip_runtime.h>
#include <hip/hip_bf16.h>
#include <cstdint>

constexpr int BATCH = 4;
constexpr int CDIM  = 512;
constexpr int NHEAD = 8;
constexpr int HD    = 64;
constexpr int FSP   = 56;
constexpr int NTOK  = FSP * FSP;  // 3136
constexpr int KH    = 28;
constexpr int KNTOK = KH * KH;    // 784
constexpr float SCALE_ATT = 0.125f;
constexpr float NEG_BIG = -1e30f;

typedef __attribute__((ext_vector_type(8))) short  short8;
typedef __attribute__((ext_vector_type(4))) float  floatx4;
typedef unsigned short u16;

__device__ __forceinline__ u16 f2bf(float f) {
  union { float f; uint32_t u; } v; v.f = f;
  uint32_t u = v.u;
  return (u16)((u + 0x7fffu + ((u >> 16) & 1u)) >> 16);
}
__device__ __forceinline__ float bf2f(u16 h) {
  union { uint32_t u; float f; } v; v.u = ((uint32_t)h) << 16;
  return v.f;
}

// ---------------------------------------------------------------------------
// P0: transpose + split fp32 [R][C] -> bf16 hi/lo [C][R].  64x64 tiles.
// Used for x (per batch) and Wq/Wkv/Wp (single).
// ---------------------------------------------------------------------------
__global__ __launch_bounds__(256) void k_tsplit(const float* __restrict__ in,
                                                u16* __restrict__ oh,
                                                u16* __restrict__ ol,
                                                int R, int C,
                                                size_t inb, size_t outb) {
  __shared__ float t[64][65];
  const int tid = threadIdx.x;
  in += (size_t)blockIdx.z * inb;
  oh += (size_t)blockIdx.z * outb;
  ol += (size_t)blockIdx.z * outb;
  const int r0 = blockIdx.x * 64, c0 = blockIdx.y * 64;
  const int rr = tid >> 2, cs = (tid & 3) * 16;
  const float* src = in + (size_t)(r0 + rr) * C + c0 + cs;
#pragma unroll
  for (int j = 0; j < 16; j += 4) *(float4*)&t[rr][cs + j] = *(const float4*)&src[j];
  __syncthreads();
  u16* dh = oh + (size_t)(c0 + rr) * R + r0 + cs;
  u16* dl = ol + (size_t)(c0 + rr) * R + r0 + cs;
#pragma unroll
  for (int j = 0; j < 16; ++j) {
    const float v = t[cs + j][rr];
    const u16 hi = f2bf(v);
    dh[j] = hi;
    dl[j] = f2bf(v - bf2f(hi));
  }
}

// ---------------------------------------------------------------------------
// P1: Wsr (o, c, 2, 2) -> hi/lo [o][k'] with k' = (di*2+dj)*512 + c.
// ---------------------------------------------------------------------------
__global__ __launch_bounds__(256) void k_srprep(const float* __restrict__ Wsr,
                                                u16* __restrict__ oh,
                                                u16* __restrict__ ol) {
  const int o = blockIdx.x;
  const float* src = Wsr + (size_t)o * 2048;
  u16* dh = oh + (size_t)o * 2048;
  u16* dl = ol + (size_t)o * 2048;
  for (int kp = threadIdx.x; kp < 2048; kp += 256) {
    const int dd = kp >> 9, c = kp & 511;
    const float v = src[c * 4 + dd];
    const u16 hi = f2bf(v);
    dh[kp] = hi;
    dl[kp] = f2bf(v - bf2f(hi));
  }
}

// ---------------------------------------------------------------------------
// Shared MFMA core: 128x128 tile, BK=32, 4 waves (2x2), 3-term bf16 split.
// LDS row stride 40 shorts (80B): frag reads 2-way conflict only (free).
// ---------------------------------------------------------------------------
#define GSTR 40

__device__ __forceinline__ void mma_tiles(const u16 (*__restrict__ Ah)[GSTR],
                                          const u16 (*__restrict__ Al)[GSTR],
                                          const u16 (*__restrict__ Bh)[GSTR],
                                          const u16 (*__restrict__ Bl)[GSTR],
                                          int wm, int wn, int quad, int tx,
                                          floatx4 acc[4][4]) {
  short8 ah[4], al[4];
#pragma unroll
  for (int i = 0; i < 4; ++i) {
    ah[i] = *(const short8*)&Ah[wm * 64 + i * 16 + tx][quad * 8];
    al[i] = *(const short8*)&Al[wm * 64 + i * 16 + tx][quad * 8];
  }
#pragma unroll
  for (int j = 0; j < 4; ++j) {
    const short8 bh = *(const short8*)&Bh[wn * 64 + j * 16 + tx][quad * 8];
    const short8 bl = *(const short8*)&Bl[wn * 64 + j * 16 + tx][quad * 8];
#pragma unroll
    for (int i = 0; i < 4; ++i) {
      acc[i][j] = __builtin_amdgcn_mfma_f32_16x16x32_bf16(ah[i], bh, acc[i][j], 0, 0, 0);
      acc[i][j] = __builtin_amdgcn_mfma_f32_16x16x32_bf16(ah[i], bl, acc[i][j], 0, 0, 0);
      acc[i][j] = __builtin_amdgcn_mfma_f32_16x16x32_bf16(al[i], bh, acc[i][j], 0, 0, 0);
    }
  }
}

#define GEMM_PRE()                                                        \
  const int tid = threadIdx.x, lane = tid & 63, wv = tid >> 6;            \
  const int wm = wv & 1, wn = wv >> 1, quad = lane >> 4, tx = lane & 15;  \
  const int sr = tid >> 1, ss = (tid & 1) * 16;                           \
  floatx4 acc[4][4];                                                      \
  _Pragma("unroll") for (int i = 0; i < 4; ++i)                           \
  _Pragma("unroll") for (int j = 0; j < 4; ++j)                           \
      acc[i][j] = (floatx4){0.f, 0.f, 0.f, 0.f};

#define STAGE4(dsth, dstl, gh, gl, off)                                   \
  *(short8*)&dsth[sr][ss]     = *(const short8*)&gh[off];                 \
  *(short8*)&dsth[sr][ss + 8] = *(const short8*)&gh[(off) + 8];           \
  *(short8*)&dstl[sr][ss]     = *(const short8*)&gl[off];                 \
  *(short8*)&dstl[sr][ss + 8] = *(const short8*)&gl[(off) + 8];

// ---------------------------------------------------------------------------
// K1: Q projection (MFMA).  A = xT[b] (3136 x 512 hi/lo), B = WqT (512 x 512).
// Output: Qhi/Qlo [b][n][512].
// ---------------------------------------------------------------------------
__global__ __launch_bounds__(256) void k_qproj(const u16* __restrict__ xh,
                                               const u16* __restrict__ xl,
                                               const u16* __restrict__ wh,
                                               const u16* __restrict__ wl,
                                               u16* __restrict__ Qh,
                                               u16* __restrict__ Ql) {
  __shared__ u16 Ahs[128][GSTR], Als[128][GSTR], Bhs[128][GSTR], Bls[128][GSTR];
  const int b = blockIdx.z, m0 = blockIdx.x * 128, n0 = blockIdx.y * 128;
  GEMM_PRE();
  const u16* xbh = xh + (size_t)b * NTOK * CDIM;
  const u16* xbl = xl + (size_t)b * NTOK * CDIM;
  int arow = m0 + sr; if (arow >= NTOK) arow = NTOK - 1;
  const size_t abase = (size_t)arow * CDIM + ss;
  const size_t bbase = (size_t)(n0 + sr) * CDIM + ss;
  for (int k0 = 0; k0 < CDIM; k0 += 32) {
    STAGE4(Ahs, Als, xbh, xbl, abase + k0);
    STAGE4(Bhs, Bls, wh, wl, bbase + k0);
    __syncthreads();
    mma_tiles(Ahs, Als, Bhs, Bls, wm, wn, quad, tx, acc);
    __syncthreads();
  }
  u16* qhB = Qh + (size_t)b * NTOK * CDIM;
  u16* qlB = Ql + (size_t)b * NTOK * CDIM;
#pragma unroll
  for (int i = 0; i < 4; ++i)
#pragma unroll
    for (int rg = 0; rg < 4; ++rg) {
      const int m = m0 + wm * 64 + i * 16 + quad * 4 + rg;
      if (m >= NTOK) continue;
#pragma unroll
      for (int j = 0; j < 4; ++j) {
        const int col = n0 + wn * 64 + j * 16 + tx;
        const float v = acc[i][j][rg];
        const u16 hi = f2bf(v);
        qhB[(size_t)m * CDIM + col] = hi;
        qlB[(size_t)m * CDIM + col] = f2bf(v - bf2f(hi));
      }
    }
}

// ---------------------------------------------------------------------------
// K2a: SR conv as MFMA GEMM.  A rows gathered from xT (k' = dd*512+c),
// B = WsrP (512 x 2048).  Output XR fp32 (+b_sr), pre-LN.
// ---------------------------------------------------------------------------
__global__ __launch_bounds__(256) void k_srconv(const u16* __restrict__ xh,
                                                const u16* __restrict__ xl,
                                                const u16* __restrict__ wh,
                                                const u16* __restrict__ wl,
                                                const float* __restrict__ b_sr,
                                                float* __restrict__ XR) {
  __shared__ u16 Ahs[128][GSTR], Als[128][GSTR], Bhs[128][GSTR], Bls[128][GSTR];
  const int b = blockIdx.z, m0 = blockIdx.x * 128, n0 = blockIdx.y * 128;
  GEMM_PRE();
  const u16* xbh = xh + (size_t)b * NTOK * CDIM;
  const u16* xbl = xl + (size_t)b * NTOK * CDIM;
  int am = m0 + sr; if (am >= KNTOK) am = 0;
  const int ii = am / KH, jj = am % KH;
  const int sp0 = 112 * ii + 2 * jj;
  const size_t bbase = (size_t)(n0 + sr) * 2048 + ss;
  for (int k0 = 0; k0 < 2048; k0 += 32) {
    const int dd = k0 >> 9;
    const int sp = sp0 + (dd >> 1) * FSP + (dd & 1);
    const size_t aoff = (size_t)sp * CDIM + (k0 & 511) + ss;
    STAGE4(Ahs, Als, xbh, xbl, aoff);
    STAGE4(Bhs, Bls, wh, wl, bbase + k0);
    __syncthreads();
    mma_tiles(Ahs, Als, Bhs, Bls, wm, wn, quad, tx, acc);
    __syncthreads();
  }
  float* xrB = XR + (size_t)b * KNTOK * CDIM;
#pragma unroll
  for (int i = 0; i < 4; ++i)
#pragma unroll
    for (int rg = 0; rg < 4; ++rg) {
      const int m = m0 + wm * 64 + i * 16 + quad * 4 + rg;
      if (m >= KNTOK) continue;
#pragma unroll
      for (int j = 0; j < 4; ++j) {
        const int col = n0 + wn * 64 + j * 16 + tx;
        xrB[(size_t)m * CDIM + col] = acc[i][j][rg] + b_sr[col];
      }
    }
}

// ---------------------------------------------------------------------------
// K2b: LayerNorm over 512 channels; outputs bf16 hi/lo split.
// ---------------------------------------------------------------------------
__global__ __launch_bounds__(256) void k_ln(const float* __restrict__ XR,
                                            const float* __restrict__ gamma,
                                            const float* __restrict__ beta,
                                            u16* __restrict__ oh,
                                            u16* __restrict__ ol) {
  const int row = blockIdx.x;
  const float* p = XR + (size_t)row * CDIM;
  const int tid = threadIdx.x;
  const float v0 = p[tid], v1 = p[tid + 256];
  float s = v0 + v1;
  float s2 = v0 * v0 + v1 * v1;
#pragma unroll
  for (int mask = 32; mask >= 1; mask >>= 1) {
    s  += __shfl_xor(s, mask, 64);
    s2 += __shfl_xor(s2, mask, 64);
  }
  __shared__ float ws[4], ws2[4];
  const int wid = tid >> 6;
  if ((tid & 63) == 0) { ws[wid] = s; ws2[wid] = s2; }
  __syncthreads();
  const float ts  = ws[0] + ws[1] + ws[2] + ws[3];
  const float ts2 = ws2[0] + ws2[1] + ws2[2] + ws2[3];
  const float mu  = ts * (1.f / CDIM);
  const float var = ts2 * (1.f / CDIM) - mu * mu;
  const float rs  = rsqrtf(var + 1e-5f);
  const float y0 = (v0 - mu) * rs * gamma[tid] + beta[tid];
  const float y1 = (v1 - mu) * rs * gamma[tid + 256] + beta[tid + 256];
  const size_t base = (size_t)row * CDIM;
  u16 h0 = f2bf(y0), h1 = f2bf(y1);
  oh[base + tid] = h0;        ol[base + tid] = f2bf(y0 - bf2f(h0));
  oh[base + tid + 256] = h1;  ol[base + tid + 256] = f2bf(y1 - bf2f(h1));
}

// ---------------------------------------------------------------------------
// K2c: KV projection (MFMA) + scatter.  A = XRhi/lo (784x512), B = WkvT
// (1024x512).  K -> hi/lo [b][h][m][d]; V -> bf16 transposed [b][h][d][m].
// ---------------------------------------------------------------------------
__global__ __launch_bounds__(256) void k_kvproj(const u16* __restrict__ ah_,
                                                const u16* __restrict__ al_,
                                                const u16* __restrict__ wh,
                                                const u16* __restrict__ wl,
                                                u16* __restrict__ KhO,
                                                u16* __restrict__ KlO,
                                                u16* __restrict__ VtO) {
  __shared__ u16 Ahs[128][GSTR], Als[128][GSTR], Bhs[128][GSTR], Bls[128][GSTR];
  const int b = blockIdx.z, m0 = blockIdx.x * 128, n0 = blockIdx.y * 128;
  GEMM_PRE();
  const u16* xbh = ah_ + (size_t)b * KNTOK * CDIM;
  const u16* xbl = al_ + (size_t)b * KNTOK * CDIM;
  int arow = m0 + sr; if (arow >= KNTOK) arow = KNTOK - 1;
  const size_t abase = (size_t)arow * CDIM + ss;
  const size_t bbase = (size_t)(n0 + sr) * CDIM + ss;
  for (int k0 = 0; k0 < CDIM; k0 += 32) {
    STAGE4(Ahs, Als, xbh, xbl, abase + k0);
    STAGE4(Bhs, Bls, wh, wl, bbase + k0);
    __syncthreads();
    mma_tiles(Ahs, Als, Bhs, Bls, wm, wn, quad, tx, acc);
    __syncthreads();
  }
#pragma unroll
  for (int i = 0; i < 4; ++i)
#pragma unroll
    for (int rg = 0; rg < 4; ++rg) {
      const int m = m0 + wm * 64 + i * 16 + quad * 4 + rg;
      if (m >= KNTOK) continue;
#pragma unroll
      for (int j = 0; j < 4; ++j) {
        const int o2 = n0 + wn * 64 + j * 16 + tx;
        const int d = o2 >> 4, hh = (o2 >> 1) & 7;
        const float v = acc[i][j][rg];
        if (o2 & 1) {
          VtO[((size_t)(b * NHEAD + hh) * HD + d) * KNTOK + m] = f2bf(v);
        } else {
          const size_t base = ((size_t)(b * NHEAD + hh) * KNTOK + m) * HD + d;
          const u16 hi = f2bf(v);
          KhO[base] = hi;
          KlO[base] = f2bf(v - bf2f(hi));
        }
      }
    }
}

// ---------------------------------------------------------------------------
// K3: relative-position bias gather -> biasM[n][m] fp32.
// ---------------------------------------------------------------------------
__global__ __launch_bounds__(256) void k_bias(const int* __restrict__ rel,
                                              const float* __restrict__ pos,
                                              float* __restrict__ biasM) {
  const int n = blockIdx.x;
  for (int m = threadIdx.x; m < KNTOK; m += 256) {
    const size_t o = ((size_t)n * NTOK + m) * 2;
    biasM[(size_t)n * KNTOK + m] = pos[rel[o] * 111 + rel[o + 1]];
  }
}

// ---------------------------------------------------------------------------
// K4: MFMA flash attention, all-bf16 staging (no conversions in loop).
// Grid (32 = b*8+h, 49 = n-tile): consecutive blocks share biasM rows; each
// XCD (= h) keeps its head's K/V L2-resident.
// ---------------------------------------------------------------------------
#define LSTR 72
__global__ __launch_bounds__(256) void k_attn(const u16* __restrict__ Qh,
                                              const u16* __restrict__ Ql,
                                              const u16* __restrict__ Kh,
                                              const u16* __restrict__ Kl,
                                              const u16* __restrict__ Vt,
                                              const float* __restrict__ biasM,
                                              u16* __restrict__ Oh,
                                              u16* __restrict__ Ol) {
  __shared__ u16 Qhs[64][LSTR], Qls[64][LSTR], Khs[64][LSTR], Kls[64][LSTR];
  __shared__ u16 Vts[64][LSTR];
  __shared__ u16 Ps[4][16][LSTR];
  const int b = blockIdx.x >> 3, h = blockIdx.x & 7;
  const int n0 = blockIdx.y * 64;
  const int tid = threadIdx.x, lane = tid & 63, wv = tid >> 6;
  const int quad = lane >> 4, tx = lane & 15;
  const int rr = tid >> 2, sg = (tid & 3) * 16;

  const u16* qhB = Qh + ((size_t)b * NTOK + n0) * CDIM + h * HD;
  const u16* qlB = Ql + ((size_t)b * NTOK + n0) * CDIM + h * HD;
  const u16* khB = Kh + (size_t)(b * NHEAD + h) * KNTOK * HD;
  const u16* klB = Kl + (size_t)(b * NHEAD + h) * KNTOK * HD;
  const u16* vtB = Vt + (size_t)(b * NHEAD + h) * HD * KNTOK;

  {
    const size_t off = (size_t)rr * CDIM + sg;
    *(short8*)&Qhs[rr][sg]     = *(const short8*)&qhB[off];
    *(short8*)&Qhs[rr][sg + 8] = *(const short8*)&qhB[off + 8];
    *(short8*)&Qls[rr][sg]     = *(const short8*)&qlB[off];
    *(short8*)&Qls[rr][sg + 8] = *(const short8*)&qlB[off + 8];
  }

  floatx4 acc_o[4];
#pragma unroll
  for (int t = 0; t < 4; ++t) acc_o[t] = (floatx4){0.f, 0.f, 0.f, 0.f};
  float m_run[4] = {NEG_BIG, NEG_BIG, NEG_BIG, NEG_BIG};
  float l_run[4] = {0.f, 0.f, 0.f, 0.f};
  __syncthreads();

  for (int jc = 0; jc < 13; ++jc) {
    const int mb = jc * 64;
    const short8 z = {0, 0, 0, 0, 0, 0, 0, 0};
    {
      const int m = mb + rr;
      if (m < KNTOK) {
        const size_t off = (size_t)m * HD + sg;
        *(short8*)&Khs[rr][sg]     = *(const short8*)&khB[off];
        *(short8*)&Khs[rr][sg + 8] = *(const short8*)&khB[off + 8];
        *(short8*)&Kls[rr][sg]     = *(const short8*)&klB[off];
        *(short8*)&Kls[rr][sg + 8] = *(const short8*)&klB[off + 8];
      } else {
        *(short8*)&Khs[rr][sg] = z; *(short8*)&Khs[rr][sg + 8] = z;
        *(short8*)&Kls[rr][sg] = z; *(short8*)&Kls[rr][sg + 8] = z;
      }
      if (mb + sg < KNTOK) {
        const size_t voff = (size_t)rr * KNTOK + mb + sg;
        *(short8*)&Vts[rr][sg]     = *(const short8*)&vtB[voff];
        *(short8*)&Vts[rr][sg + 8] = *(const short8*)&vtB[voff + 8];
      } else {
        *(short8*)&Vts[rr][sg] = z; *(short8*)&Vts[rr][sg + 8] = z;
      }
    }
    __syncthreads();

    floatx4 sc[4];
#pragma unroll
    for (int t = 0; t < 4; ++t) sc[t] = (floatx4){0.f, 0.f, 0.f, 0.f};
#pragma unroll
    for (int ks = 0; ks < 2; ++ks) {
      const int kk = ks * 32 + quad * 8;
      const short8 aqh = *(const short8*)&Qhs[wv * 16 + tx][kk];
      const short8 aql = *(const short8*)&Qls[wv * 16 + tx][kk];
#pragma unroll
      for (int t = 0; t < 4; ++t) {
        const short8 bkh = *(const short8*)&Khs[t * 16 + tx][kk];
        const short8 bkl = *(const short8*)&Kls[t * 16 + tx][kk];
        sc[t] = __builtin_amdgcn_mfma_f32_16x16x32_bf16(aqh, bkh, sc[t], 0, 0, 0);
        sc[t] = __builtin_amdgcn_mfma_f32_16x16x32_bf16(aqh, bkl, sc[t], 0, 0, 0);
        sc[t] = __builtin_amdgcn_mfma_f32_16x16x32_bf16(aql, bkh, sc[t], 0, 0, 0);
      }
    }

#pragma unroll
    for (int r = 0; r < 4; ++r) {
      const int grow = n0 + wv * 16 + quad * 4 + r;
      const float* brow = biasM + (size_t)grow * KNTOK;
      float sv[4];
#pragma unroll
      for (int t = 0; t < 4; ++t) {
        const int col = mb + t * 16 + tx;
        sv[t] = (col < KNTOK) ? (sc[t][r] * SCALE_ATT + brow[col]) : NEG_BIG;
      }
      float mx = fmaxf(fmaxf(sv[0], sv[1]), fmaxf(sv[2], sv[3]));
#pragma unroll
      for (int msk = 1; msk < 16; msk <<= 1) mx = fmaxf(mx, __shfl_xor(mx, msk, 64));
      const float mnew = fmaxf(m_run[r], mx);
      const float alpha = __expf(m_run[r] - mnew);
      float lsum = 0.f;
#pragma unroll
      for (int t = 0; t < 4; ++t) {
        const float pv = __expf(sv[t] - mnew);
        lsum += pv;
        Ps[wv][quad * 4 + r][t * 16 + tx] = f2bf(pv);
      }
#pragma unroll
      for (int msk = 1; msk < 16; msk <<= 1) lsum += __shfl_xor(lsum, msk, 64);
      l_run[r] = l_run[r] * alpha + lsum;
      m_run[r] = mnew;
#pragma unroll
      for (int t = 0; t < 4; ++t) acc_o[t][r] *= alpha;
    }

#pragma unroll
    for (int ks = 0; ks < 2; ++ks) {
      const int kk = ks * 32 + quad * 8;
      const short8 ap = *(const short8*)&Ps[wv][tx][kk];
#pragma unroll
      for (int t = 0; t < 4; ++t) {
        const short8 bv = *(const short8*)&Vts[t * 16 + tx][kk];
        acc_o[t] = __builtin_amdgcn_mfma_f32_16x16x32_bf16(ap, bv, acc_o[t], 0, 0, 0);
      }
    }
    __syncthreads();
  }

#pragma unroll
  for (int r = 0; r < 4; ++r) {
    const float inv = 1.f / l_run[r];
    const int grow = n0 + wv * 16 + quad * 4 + r;
    const size_t base = ((size_t)b * NTOK + grow) * CDIM + h * HD;
#pragma unroll
    for (int t = 0; t < 4; ++t) {
      const float o = acc_o[t][r] * inv;
      const u16 hi = f2bf(o);
      Oh[base + t * 16 + tx] = hi;
      Ol[base + t * 16 + tx] = f2bf(o - bf2f(hi));
    }
  }
}

// ---------------------------------------------------------------------------
// K5: output projection (MFMA).  A = Oghi/lo, B = WpT.  +bp, store fp32
// transposed to (b, co, n) with per-lane float4 along n.
// ---------------------------------------------------------------------------
__global__ __launch_bounds__(256) void k_outproj(const u16* __restrict__ ah_,
                                                 const u16* __restrict__ al_,
                                                 const u16* __restrict__ wh,
                                                 const u16* __restrict__ wl,
                                                 const float* __restrict__ bp,
                                                 float* __restrict__ out) {
  __shared__ u16 Ahs[128][GSTR], Als[128][GSTR], Bhs[128][GSTR], Bls[128][GSTR];
  const int b = blockIdx.z, m0 = blockIdx.x * 128, n0 = blockIdx.y * 128;
  GEMM_PRE();
  const u16* xbh = ah_ + (size_t)b * NTOK * CDIM;
  const u16* xbl = al_ + (size_t)b * NTOK * CDIM;
  int arow = m0 + sr; if (arow >= NTOK) arow = NTOK - 1;
  const size_t abase = (size_t)arow * CDIM + ss;
  const size_t bbase = (size_t)(n0 + sr) * CDIM + ss;
  for (int k0 = 0; k0 < CDIM; k0 += 32) {
    STAGE4(Ahs, Als, xbh, xbl, abase + k0);
    STAGE4(Bhs, Bls, wh, wl, bbase + k0);
    __syncthreads();
    mma_tiles(Ahs, Als, Bhs, Bls, wm, wn, quad, tx, acc);
    __syncthreads();
  }
#pragma unroll
  for (int j = 0; j < 4; ++j) {
    const int co = n0 + wn * 64 + j * 16 + tx;
    const float bpv = bp[co];
    float* obase = out + ((size_t)b * CDIM + co) * NTOK;
#pragma unroll
    for (int i = 0; i < 4; ++i) {
      const int mb4 = m0 + wm * 64 + i * 16 + quad * 4;
      if (mb4 < NTOK) {
        floatx4 v = acc[i][j] + bpv;
        *(floatx4*)&obase[mb4] = v;
      }
    }
  }
}

// ---------------------------------------------------------------------------
extern "C" void kernel_launch(void* const* d_in, const int* in_sizes, int n_in,
                              void* d_out, int out_size, void* d_ws, size_t ws_size,
                              hipStream_t stream) {
  const float* x     = (const float*)d_in[0];
  const float* Wq    = (const float*)d_in[1];
  const float* Wkv   = (const float*)d_in[2];
  const float* Wsr   = (const float*)d_in[3];
  const float* b_sr  = (const float*)d_in[4];
  const float* gamma = (const float*)d_in[5];
  const float* beta  = (const float*)d_in[6];
  const float* Wp    = (const float*)d_in[7];
  const float* bp    = (const float*)d_in[8];
  const float* pos   = (const float*)d_in[9];
  const int*   rel   = (const int*)d_in[10];
  float* out = (float*)d_out;

  char* p = (char*)d_ws;
  auto alloc = [&](size_t bytes) -> void* {
    void* r = (void*)p;
    p += (bytes + 255) & ~(size_t)255;
    return r;
  };
  const size_t SZ_BNC = (size_t)BATCH * NTOK * CDIM;   // 6.42M elems
  const size_t SZ_BKC = (size_t)BATCH * KNTOK * CDIM;  // 1.61M elems
  const size_t SZ_KV  = (size_t)BATCH * NHEAD * KNTOK * HD;

  u16* xThi  = (u16*)alloc(SZ_BNC * 2);   // aliased later as Oghi
  u16* xTlo  = (u16*)alloc(SZ_BNC * 2);   // aliased later as Oglo
  u16* WqTh  = (u16*)alloc(512 * 512 * 2);
  u16* WqTl  = (u16*)alloc(512 * 512 * 2);
  u16* WkvTh = (u16*)alloc(1024 * 512 * 2);
  u16* WkvTl = (u16*)alloc(1024 * 512 * 2);
  u16* WpTh  = (u16*)alloc(512 * 512 * 2);
  u16* WpTl  = (u16*)alloc(512 * 512 * 2);
  u16* WsrPh = (u16*)alloc(512 * 2048 * 2);
  u16* WsrPl = (u16*)alloc(512 * 2048 * 2);
  u16* Qhi   = (u16*)alloc(SZ_BNC * 2);
  u16* Qlo   = (u16*)alloc(SZ_BNC * 2);
  float* XR  = (float*)alloc(SZ_BKC * 4); // aliased: Khi/Klo after k_ln
  u16* XRhi  = (u16*)alloc(SZ_BKC * 2);
  u16* XRlo  = (u16*)alloc(SZ_BKC * 2);
  u16* Vt    = (u16*)alloc(SZ_KV * 2);
  float* biasM = (float*)alloc((size_t)NTOK * KNTOK * 4);

  // aliases (lifetimes disjoint, stream-ordered):
  u16* Khi  = (u16*)XR;          // XR fp32 dead after k_ln
  u16* Klo  = Khi + SZ_KV;
  u16* Oghi = xThi;              // xT dead after k_qproj + k_srconv
  u16* Oglo = xTlo;

  const dim3 blk(256);
  // prep
  k_tsplit<<<dim3(8, 49, BATCH), blk, 0, stream>>>(x, xThi, xTlo, CDIM, NTOK,
                                                   (size_t)CDIM * NTOK, (size_t)NTOK * CDIM);
  k_tsplit<<<dim3(8, 8, 1),  blk, 0, stream>>>(Wq,  WqTh,  WqTl,  512, 512,  0, 0);
  k_tsplit<<<dim3(8, 16, 1), blk, 0, stream>>>(Wkv, WkvTh, WkvTl, 512, 1024, 0, 0);
  k_tsplit<<<dim3(8, 8, 1),  blk, 0, stream>>>(Wp,  WpTh,  WpTl,  512, 512,  0, 0);
  k_srprep<<<dim3(512), blk, 0, stream>>>(Wsr, WsrPh, WsrPl);
  k_bias  <<<dim3(NTOK), blk, 0, stream>>>(rel, pos, biasM);
  // main pipeline
  k_qproj <<<dim3(25, 4, BATCH), blk, 0, stream>>>(xThi, xTlo, WqTh, WqTl, Qhi, Qlo);
  k_srconv<<<dim3(7, 4, BATCH),  blk, 0, stream>>>(xThi, xTlo, WsrPh, WsrPl, b_sr, XR);
  k_ln    <<<dim3(BATCH * KNTOK), blk, 0, stream>>>(XR, gamma, beta, XRhi, XRlo);
  k_kvproj<<<dim3(7, 8, BATCH),  blk, 0, stream>>>(XRhi, XRlo, WkvTh, WkvTl, Khi, Klo, Vt);
  k_attn  <<<dim3(BATCH * NHEAD, 49), blk, 0, stream>>>(Qhi, Qlo, Khi, Klo, Vt, biasM, Oghi, Oglo);
  k_outproj<<<dim3(25, 4, BATCH), blk, 0, stream>>>(Oghi, Oglo, WpTh, WpTl, bp, out);
}

// Round 4
// 375.315 us; speedup vs baseline: 8.1771x; 1.3650x over previous
//
#include <hip/hip_runtime.h>
#include <hip/hip_bf16.h>
#include <cstdint>

constexpr int BATCH = 4;
constexpr int CDIM  = 512;
constexpr int NHEAD = 8;
constexpr int HD    = 64;
constexpr int FSP   = 56;
constexpr int NTOK  = FSP * FSP;  // 3136
constexpr int KH    = 28;
constexpr int KNTOK = KH * KH;    // 784
constexpr float SCALE_ATT = 0.125f;
constexpr float NEG_BIG = -1e30f;

typedef _Float16 f16;
typedef __attribute__((ext_vector_type(8))) _Float16 half8;
typedef __attribute__((ext_vector_type(4))) float  floatx4;

// ---------------------------------------------------------------------------
// P0: transpose fp32 [R][C] -> fp16 [C][R].  64x64 tiles.
// ---------------------------------------------------------------------------
__global__ __launch_bounds__(256) void k_tsplit(const float* __restrict__ in,
                                                f16* __restrict__ oh,
                                                int R, int C,
                                                size_t inb, size_t outb) {
  __shared__ float t[64][65];
  const int tid = threadIdx.x;
  in += (size_t)blockIdx.z * inb;
  oh += (size_t)blockIdx.z * outb;
  const int r0 = blockIdx.x * 64, c0 = blockIdx.y * 64;
  const int rr = tid >> 2, cs = (tid & 3) * 16;
  const float* src = in + (size_t)(r0 + rr) * C + c0 + cs;
#pragma unroll
  for (int j = 0; j < 16; j += 4) *(float4*)&t[rr][cs + j] = *(const float4*)&src[j];
  __syncthreads();
  f16* dh = oh + (size_t)(c0 + rr) * R + r0 + cs;
#pragma unroll
  for (int j = 0; j < 16; ++j) dh[j] = (f16)t[cs + j][rr];
}

// ---------------------------------------------------------------------------
// P1: Wsr (o, c, 2, 2) -> fp16 [o][k'] with k' = (di*2+dj)*512 + c.
// ---------------------------------------------------------------------------
__global__ __launch_bounds__(256) void k_srprep(const float* __restrict__ Wsr,
                                                f16* __restrict__ oh) {
  const int o = blockIdx.x;
  const float* src = Wsr + (size_t)o * 2048;
  f16* dh = oh + (size_t)o * 2048;
  for (int kp = threadIdx.x; kp < 2048; kp += 256) {
    const int dd = kp >> 9, c = kp & 511;
    dh[kp] = (f16)src[c * 4 + dd];
  }
}

// ---------------------------------------------------------------------------
// Shared MFMA core: 128x128 tile, BK=32, 4 waves (2x2), fp16 single-term.
// LDS row stride 40 halves (80B): frag reads 2-way conflict only (free).
// ---------------------------------------------------------------------------
#define GSTR 40

__device__ __forceinline__ void mma_tiles(const f16 (*__restrict__ Ah)[GSTR],
                                          const f16 (*__restrict__ Bh)[GSTR],
                                          int wm, int wn, int quad, int tx,
                                          floatx4 acc[4][4]) {
  half8 ah[4];
#pragma unroll
  for (int i = 0; i < 4; ++i)
    ah[i] = *(const half8*)&Ah[wm * 64 + i * 16 + tx][quad * 8];
#pragma unroll
  for (int j = 0; j < 4; ++j) {
    const half8 bh = *(const half8*)&Bh[wn * 64 + j * 16 + tx][quad * 8];
#pragma unroll
    for (int i = 0; i < 4; ++i)
      acc[i][j] = __builtin_amdgcn_mfma_f32_16x16x32_f16(ah[i], bh, acc[i][j], 0, 0, 0);
  }
}

#define GEMM_PRE()                                                        \
  const int tid = threadIdx.x, lane = tid & 63, wv = tid >> 6;            \
  const int wm = wv & 1, wn = wv >> 1, quad = lane >> 4, tx = lane & 15;  \
  const int sr = tid >> 1, ss = (tid & 1) * 16;                           \
  floatx4 acc[4][4];                                                      \
  _Pragma("unroll") for (int i = 0; i < 4; ++i)                           \
  _Pragma("unroll") for (int j = 0; j < 4; ++j)                           \
      acc[i][j] = (floatx4){0.f, 0.f, 0.f, 0.f};

#define STAGE4(dsth, gh, off)                                             \
  *(half8*)&dsth[sr][ss]     = *(const half8*)&gh[off];                   \
  *(half8*)&dsth[sr][ss + 8] = *(const half8*)&gh[(off) + 8];

// ---------------------------------------------------------------------------
// K1: Q projection (MFMA fp16).  A = xT[b] (3136x512), B = WqT (512x512).
// ---------------------------------------------------------------------------
__global__ __launch_bounds__(256) void k_qproj(const f16* __restrict__ xh,
                                               const f16* __restrict__ wh,
                                               f16* __restrict__ Qh) {
  __shared__ f16 Ahs[128][GSTR], Bhs[128][GSTR];
  const int b = blockIdx.z, m0 = blockIdx.x * 128, n0 = blockIdx.y * 128;
  GEMM_PRE();
  const f16* xbh = xh + (size_t)b * NTOK * CDIM;
  int arow = m0 + sr; if (arow >= NTOK) arow = NTOK - 1;
  const size_t abase = (size_t)arow * CDIM + ss;
  const size_t bbase = (size_t)(n0 + sr) * CDIM + ss;
  for (int k0 = 0; k0 < CDIM; k0 += 32) {
    STAGE4(Ahs, xbh, abase + k0);
    STAGE4(Bhs, wh, bbase + k0);
    __syncthreads();
    mma_tiles(Ahs, Bhs, wm, wn, quad, tx, acc);
    __syncthreads();
  }
  f16* qhB = Qh + (size_t)b * NTOK * CDIM;
#pragma unroll
  for (int i = 0; i < 4; ++i)
#pragma unroll
    for (int rg = 0; rg < 4; ++rg) {
      const int m = m0 + wm * 64 + i * 16 + quad * 4 + rg;
      if (m >= NTOK) continue;
#pragma unroll
      for (int j = 0; j < 4; ++j) {
        const int col = n0 + wn * 64 + j * 16 + tx;
        qhB[(size_t)m * CDIM + col] = (f16)acc[i][j][rg];
      }
    }
}

// ---------------------------------------------------------------------------
// K2a: SR conv as MFMA GEMM (fp16).  Output XR fp32 (+b_sr), pre-LN.
// ---------------------------------------------------------------------------
__global__ __launch_bounds__(256) void k_srconv(const f16* __restrict__ xh,
                                                const f16* __restrict__ wh,
                                                const float* __restrict__ b_sr,
                                                float* __restrict__ XR) {
  __shared__ f16 Ahs[128][GSTR], Bhs[128][GSTR];
  const int b = blockIdx.z, m0 = blockIdx.x * 128, n0 = blockIdx.y * 128;
  GEMM_PRE();
  const f16* xbh = xh + (size_t)b * NTOK * CDIM;
  int am = m0 + sr; if (am >= KNTOK) am = 0;
  const int ii = am / KH, jj = am % KH;
  const int sp0 = 112 * ii + 2 * jj;
  const size_t bbase = (size_t)(n0 + sr) * 2048 + ss;
  for (int k0 = 0; k0 < 2048; k0 += 32) {
    const int dd = k0 >> 9;
    const int sp = sp0 + (dd >> 1) * FSP + (dd & 1);
    const size_t aoff = (size_t)sp * CDIM + (k0 & 511) + ss;
    STAGE4(Ahs, xbh, aoff);
    STAGE4(Bhs, wh, bbase + k0);
    __syncthreads();
    mma_tiles(Ahs, Bhs, wm, wn, quad, tx, acc);
    __syncthreads();
  }
  float* xrB = XR + (size_t)b * KNTOK * CDIM;
#pragma unroll
  for (int i = 0; i < 4; ++i)
#pragma unroll
    for (int rg = 0; rg < 4; ++rg) {
      const int m = m0 + wm * 64 + i * 16 + quad * 4 + rg;
      if (m >= KNTOK) continue;
#pragma unroll
      for (int j = 0; j < 4; ++j) {
        const int col = n0 + wn * 64 + j * 16 + tx;
        xrB[(size_t)m * CDIM + col] = acc[i][j][rg] + b_sr[col];
      }
    }
}

// ---------------------------------------------------------------------------
// K2b: LayerNorm over 512 channels; outputs fp16.
// ---------------------------------------------------------------------------
__global__ __launch_bounds__(256) void k_ln(const float* __restrict__ XR,
                                            const float* __restrict__ gamma,
                                            const float* __restrict__ beta,
                                            f16* __restrict__ oh) {
  const int row = blockIdx.x;
  const float* p = XR + (size_t)row * CDIM;
  const int tid = threadIdx.x;
  const float v0 = p[tid], v1 = p[tid + 256];
  float s = v0 + v1;
  float s2 = v0 * v0 + v1 * v1;
#pragma unroll
  for (int mask = 32; mask >= 1; mask >>= 1) {
    s  += __shfl_xor(s, mask, 64);
    s2 += __shfl_xor(s2, mask, 64);
  }
  __shared__ float ws[4], ws2[4];
  const int wid = tid >> 6;
  if ((tid & 63) == 0) { ws[wid] = s; ws2[wid] = s2; }
  __syncthreads();
  const float ts  = ws[0] + ws[1] + ws[2] + ws[3];
  const float ts2 = ws2[0] + ws2[1] + ws2[2] + ws2[3];
  const float mu  = ts * (1.f / CDIM);
  const float var = ts2 * (1.f / CDIM) - mu * mu;
  const float rs  = rsqrtf(var + 1e-5f);
  const float y0 = (v0 - mu) * rs * gamma[tid] + beta[tid];
  const float y1 = (v1 - mu) * rs * gamma[tid + 256] + beta[tid + 256];
  const size_t base = (size_t)row * CDIM;
  oh[base + tid]       = (f16)y0;
  oh[base + tid + 256] = (f16)y1;
}

// ---------------------------------------------------------------------------
// K2c: KV projection (MFMA fp16) + scatter.  K -> fp16 [b][h][m][d];
// V -> fp16 transposed [b][h][d][m].
// ---------------------------------------------------------------------------
__global__ __launch_bounds__(256) void k_kvproj(const f16* __restrict__ ah_,
                                                const f16* __restrict__ wh,
                                                f16* __restrict__ KhO,
                                                f16* __restrict__ VtO) {
  __shared__ f16 Ahs[128][GSTR], Bhs[128][GSTR];
  const int b = blockIdx.z, m0 = blockIdx.x * 128, n0 = blockIdx.y * 128;
  GEMM_PRE();
  const f16* xbh = ah_ + (size_t)b * KNTOK * CDIM;
  int arow = m0 + sr; if (arow >= KNTOK) arow = KNTOK - 1;
  const size_t abase = (size_t)arow * CDIM + ss;
  const size_t bbase = (size_t)(n0 + sr) * CDIM + ss;
  for (int k0 = 0; k0 < CDIM; k0 += 32) {
    STAGE4(Ahs, xbh, abase + k0);
    STAGE4(Bhs, wh, bbase + k0);
    __syncthreads();
    mma_tiles(Ahs, Bhs, wm, wn, quad, tx, acc);
    __syncthreads();
  }
#pragma unroll
  for (int i = 0; i < 4; ++i)
#pragma unroll
    for (int rg = 0; rg < 4; ++rg) {
      const int m = m0 + wm * 64 + i * 16 + quad * 4 + rg;
      if (m >= KNTOK) continue;
#pragma unroll
      for (int j = 0; j < 4; ++j) {
        const int o2 = n0 + wn * 64 + j * 16 + tx;
        const int d = o2 >> 4, hh = (o2 >> 1) & 7;
        const float v = acc[i][j][rg];
        if (o2 & 1) {
          VtO[((size_t)(b * NHEAD + hh) * HD + d) * KNTOK + m] = (f16)v;
        } else {
          KhO[((size_t)(b * NHEAD + hh) * KNTOK + m) * HD + d] = (f16)v;
        }
      }
    }
}

// ---------------------------------------------------------------------------
// K3: relative-position bias gather -> biasM[n][m] fp32.
// ---------------------------------------------------------------------------
__global__ __launch_bounds__(256) void k_bias(const int* __restrict__ rel,
                                              const float* __restrict__ pos,
                                              float* __restrict__ biasM) {
  const int n = blockIdx.x;
  for (int m = threadIdx.x; m < KNTOK; m += 256) {
    const size_t o = ((size_t)n * NTOK + m) * 2;
    biasM[(size_t)n * KNTOK + m] = pos[rel[o] * 111 + rel[o + 1]];
  }
}

// ---------------------------------------------------------------------------
// K4: MFMA flash attention, fp16 single-term.
// Grid (32 = b*8+h, 49 = n-tile) for L2 locality.
// ---------------------------------------------------------------------------
#define LSTR 72
__global__ __launch_bounds__(256) void k_attn(const f16* __restrict__ Qh,
                                              const f16* __restrict__ Kh,
                                              const f16* __restrict__ Vt,
                                              const float* __restrict__ biasM,
                                              f16* __restrict__ Oh) {
  __shared__ f16 Qhs[64][LSTR], Khs[64][LSTR], Vts[64][LSTR];
  __shared__ f16 Ps[4][16][LSTR];
  const int b = blockIdx.x >> 3, h = blockIdx.x & 7;
  const int n0 = blockIdx.y * 64;
  const int tid = threadIdx.x, lane = tid & 63, wv = tid >> 6;
  const int quad = lane >> 4, tx = lane & 15;
  const int rr = tid >> 2, sg = (tid & 3) * 16;

  const f16* qhB = Qh + ((size_t)b * NTOK + n0) * CDIM + h * HD;
  const f16* khB = Kh + (size_t)(b * NHEAD + h) * KNTOK * HD;
  const f16* vtB = Vt + (size_t)(b * NHEAD + h) * HD * KNTOK;

  {
    const size_t off = (size_t)rr * CDIM + sg;
    *(half8*)&Qhs[rr][sg]     = *(const half8*)&qhB[off];
    *(half8*)&Qhs[rr][sg + 8] = *(const half8*)&qhB[off + 8];
  }

  floatx4 acc_o[4];
#pragma unroll
  for (int t = 0; t < 4; ++t) acc_o[t] = (floatx4){0.f, 0.f, 0.f, 0.f};
  float m_run[4] = {NEG_BIG, NEG_BIG, NEG_BIG, NEG_BIG};
  float l_run[4] = {0.f, 0.f, 0.f, 0.f};
  __syncthreads();

  for (int jc = 0; jc < 13; ++jc) {
    const int mb = jc * 64;
    const half8 z = {0, 0, 0, 0, 0, 0, 0, 0};
    {
      const int m = mb + rr;
      if (m < KNTOK) {
        const size_t off = (size_t)m * HD + sg;
        *(half8*)&Khs[rr][sg]     = *(const half8*)&khB[off];
        *(half8*)&Khs[rr][sg + 8] = *(const half8*)&khB[off + 8];
      } else {
        *(half8*)&Khs[rr][sg] = z; *(half8*)&Khs[rr][sg + 8] = z;
      }
      if (mb + sg < KNTOK) {
        const size_t voff = (size_t)rr * KNTOK + mb + sg;
        *(half8*)&Vts[rr][sg]     = *(const half8*)&vtB[voff];
        *(half8*)&Vts[rr][sg + 8] = *(const half8*)&vtB[voff + 8];
      } else {
        *(half8*)&Vts[rr][sg] = z; *(half8*)&Vts[rr][sg + 8] = z;
      }
    }
    __syncthreads();

    floatx4 sc[4];
#pragma unroll
    for (int t = 0; t < 4; ++t) sc[t] = (floatx4){0.f, 0.f, 0.f, 0.f};
#pragma unroll
    for (int ks = 0; ks < 2; ++ks) {
      const int kk = ks * 32 + quad * 8;
      const half8 aqh = *(const half8*)&Qhs[wv * 16 + tx][kk];
#pragma unroll
      for (int t = 0; t < 4; ++t) {
        const half8 bkh = *(const half8*)&Khs[t * 16 + tx][kk];
        sc[t] = __builtin_amdgcn_mfma_f32_16x16x32_f16(aqh, bkh, sc[t], 0, 0, 0);
      }
    }

#pragma unroll
    for (int r = 0; r < 4; ++r) {
      const int grow = n0 + wv * 16 + quad * 4 + r;
      const float* brow = biasM + (size_t)grow * KNTOK;
      float sv[4];
#pragma unroll
      for (int t = 0; t < 4; ++t) {
        const int col = mb + t * 16 + tx;
        sv[t] = (col < KNTOK) ? (sc[t][r] * SCALE_ATT + brow[col]) : NEG_BIG;
      }
      float mx = fmaxf(fmaxf(sv[0], sv[1]), fmaxf(sv[2], sv[3]));
#pragma unroll
      for (int msk = 1; msk < 16; msk <<= 1) mx = fmaxf(mx, __shfl_xor(mx, msk, 64));
      const float mnew = fmaxf(m_run[r], mx);
      const float alpha = __expf(m_run[r] - mnew);
      float lsum = 0.f;
#pragma unroll
      for (int t = 0; t < 4; ++t) {
        const float pv = __expf(sv[t] - mnew);
        lsum += pv;
        Ps[wv][quad * 4 + r][t * 16 + tx] = (f16)pv;
      }
#pragma unroll
      for (int msk = 1; msk < 16; msk <<= 1) lsum += __shfl_xor(lsum, msk, 64);
      l_run[r] = l_run[r] * alpha + lsum;
      m_run[r] = mnew;
#pragma unroll
      for (int t = 0; t < 4; ++t) acc_o[t][r] *= alpha;
    }

#pragma unroll
    for (int ks = 0; ks < 2; ++ks) {
      const int kk = ks * 32 + quad * 8;
      const half8 ap = *(const half8*)&Ps[wv][tx][kk];
#pragma unroll
      for (int t = 0; t < 4; ++t) {
        const half8 bv = *(const half8*)&Vts[t * 16 + tx][kk];
        acc_o[t] = __builtin_amdgcn_mfma_f32_16x16x32_f16(ap, bv, acc_o[t], 0, 0, 0);
      }
    }
    __syncthreads();
  }

#pragma unroll
  for (int r = 0; r < 4; ++r) {
    const float inv = 1.f / l_run[r];
    const int grow = n0 + wv * 16 + quad * 4 + r;
    const size_t base = ((size_t)b * NTOK + grow) * CDIM + h * HD;
#pragma unroll
    for (int t = 0; t < 4; ++t) {
      Oh[base + t * 16 + tx] = (f16)(acc_o[t][r] * inv);
    }
  }
}

// ---------------------------------------------------------------------------
// K5: output projection (MFMA fp16).  +bp, store fp32 transposed (b, co, n).
// ---------------------------------------------------------------------------
__global__ __launch_bounds__(256) void k_outproj(const f16* __restrict__ ah_,
                                                 const f16* __restrict__ wh,
                                                 const float* __restrict__ bp,
                                                 float* __restrict__ out) {
  __shared__ f16 Ahs[128][GSTR], Bhs[128][GSTR];
  const int b = blockIdx.z, m0 = blockIdx.x * 128, n0 = blockIdx.y * 128;
  GEMM_PRE();
  const f16* xbh = ah_ + (size_t)b * NTOK * CDIM;
  int arow = m0 + sr; if (arow >= NTOK) arow = NTOK - 1;
  const size_t abase = (size_t)arow * CDIM + ss;
  const size_t bbase = (size_t)(n0 + sr) * CDIM + ss;
  for (int k0 = 0; k0 < CDIM; k0 += 32) {
    STAGE4(Ahs, xbh, abase + k0);
    STAGE4(Bhs, wh, bbase + k0);
    __syncthreads();
    mma_tiles(Ahs, Bhs, wm, wn, quad, tx, acc);
    __syncthreads();
  }
#pragma unroll
  for (int j = 0; j < 4; ++j) {
    const int co = n0 + wn * 64 + j * 16 + tx;
    const float bpv = bp[co];
    float* obase = out + ((size_t)b * CDIM + co) * NTOK;
#pragma unroll
    for (int i = 0; i < 4; ++i) {
      const int mb4 = m0 + wm * 64 + i * 16 + quad * 4;
      if (mb4 < NTOK) {
        floatx4 v = acc[i][j] + bpv;
        *(floatx4*)&obase[mb4] = v;
      }
    }
  }
}

// ---------------------------------------------------------------------------
extern "C" void kernel_launch(void* const* d_in, const int* in_sizes, int n_in,
                              void* d_out, int out_size, void* d_ws, size_t ws_size,
                              hipStream_t stream) {
  const float* x     = (const float*)d_in[0];
  const float* Wq    = (const float*)d_in[1];
  const float* Wkv   = (const float*)d_in[2];
  const float* Wsr   = (const float*)d_in[3];
  const float* b_sr  = (const float*)d_in[4];
  const float* gamma = (const float*)d_in[5];
  const float* beta  = (const float*)d_in[6];
  const float* Wp    = (const float*)d_in[7];
  const float* bp    = (const float*)d_in[8];
  const float* pos   = (const float*)d_in[9];
  const int*   rel   = (const int*)d_in[10];
  float* out = (float*)d_out;

  char* p = (char*)d_ws;
  auto alloc = [&](size_t bytes) -> void* {
    void* r = (void*)p;
    p += (bytes + 255) & ~(size_t)255;
    return r;
  };
  const size_t SZ_BNC = (size_t)BATCH * NTOK * CDIM;
  const size_t SZ_BKC = (size_t)BATCH * KNTOK * CDIM;
  const size_t SZ_KV  = (size_t)BATCH * NHEAD * KNTOK * HD;

  f16* xT    = (f16*)alloc(SZ_BNC * 2);    // aliased later as Og
  f16* WqT   = (f16*)alloc(512 * 512 * 2);
  f16* WkvT  = (f16*)alloc(1024 * 512 * 2);
  f16* WpT   = (f16*)alloc(512 * 512 * 2);
  f16* WsrP  = (f16*)alloc(512 * 2048 * 2);
  f16* Qh    = (f16*)alloc(SZ_BNC * 2);
  float* XR  = (float*)alloc(SZ_BKC * 4);  // aliased: Kh after k_ln
  f16* XRh   = (f16*)alloc(SZ_BKC * 2);
  f16* Vt    = (f16*)alloc(SZ_KV * 2);
  float* biasM = (float*)alloc((size_t)NTOK * KNTOK * 4);

  f16* Kh = (f16*)XR;   // XR fp32 dead after k_ln (3.2MB <= 6.4MB)
  f16* Og = xT;         // xT dead after k_qproj + k_srconv

  const dim3 blk(256);
  k_tsplit<<<dim3(8, 49, BATCH), blk, 0, stream>>>(x, xT, CDIM, NTOK,
                                                   (size_t)CDIM * NTOK, (size_t)NTOK * CDIM);
  k_tsplit<<<dim3(8, 8, 1),  blk, 0, stream>>>(Wq,  WqT,  512, 512,  0, 0);
  k_tsplit<<<dim3(8, 16, 1), blk, 0, stream>>>(Wkv, WkvT, 512, 1024, 0, 0);
  k_tsplit<<<dim3(8, 8, 1),  blk, 0, stream>>>(Wp,  WpT,  512, 512,  0, 0);
  k_srprep<<<dim3(512), blk, 0, stream>>>(Wsr, WsrP);
  k_bias  <<<dim3(NTOK), blk, 0, stream>>>(rel, pos, biasM);

  k_qproj <<<dim3(25, 4, BATCH), blk, 0, stream>>>(xT, WqT, Qh);
  k_srconv<<<dim3(7, 4, BATCH),  blk, 0, stream>>>(xT, WsrP, b_sr, XR);
  k_ln    <<<dim3(BATCH * KNTOK), blk, 0, stream>>>(XR, gamma, beta, XRh);
  k_kvproj<<<dim3(7, 8, BATCH),  blk, 0, stream>>>(XRh, WkvT, Kh, Vt);
  k_attn  <<<dim3(BATCH * NHEAD, 49), blk, 0, stream>>>(Qh, Kh, Vt, biasM, Og);
  k_outproj<<<dim3(25, 4, BATCH), blk, 0, stream>>>(Og, WpT, bp, out);
}

// Round 5
// 320.086 us; speedup vs baseline: 9.5881x; 1.1725x over previous
//
#include <hip/hip_runtime.h>
#include <hip/hip_bf16.h>
#include <cstdint>

constexpr int BATCH = 4;
constexpr int CDIM  = 512;
constexpr int NHEAD = 8;
constexpr int HD    = 64;
constexpr int FSP   = 56;
constexpr int NTOK  = FSP * FSP;  // 3136
constexpr int KH    = 28;
constexpr int KNTOK = KH * KH;    // 784
constexpr float SCALE_ATT = 0.125f;
constexpr int BIAS_LD = 832;      // 13 chunks * 64, padded cols baked to -3e4

typedef _Float16 f16;
typedef __attribute__((ext_vector_type(8))) _Float16 half8;
typedef __attribute__((ext_vector_type(4))) float  floatx4;

// ---------------------------------------------------------------------------
// P0: transpose fp32 [R][C] -> fp16 [C][R].  64x64 tiles.
// ---------------------------------------------------------------------------
__global__ __launch_bounds__(256) void k_tsplit(const float* __restrict__ in,
                                                f16* __restrict__ oh,
                                                int R, int C,
                                                size_t inb, size_t outb) {
  __shared__ float t[64][65];
  const int tid = threadIdx.x;
  in += (size_t)blockIdx.z * inb;
  oh += (size_t)blockIdx.z * outb;
  const int r0 = blockIdx.x * 64, c0 = blockIdx.y * 64;
  const int rr = tid >> 2, cs = (tid & 3) * 16;
  const float* src = in + (size_t)(r0 + rr) * C + c0 + cs;
#pragma unroll
  for (int j = 0; j < 16; j += 4) *(float4*)&t[rr][cs + j] = *(const float4*)&src[j];
  __syncthreads();
  f16* dh = oh + (size_t)(c0 + rr) * R + r0 + cs;
#pragma unroll
  for (int j = 0; j < 16; ++j) dh[j] = (f16)t[cs + j][rr];
}

// ---------------------------------------------------------------------------
// P1: Wsr (o, c, 2, 2) -> fp16 [o][k'] with k' = (di*2+dj)*512 + c.
// ---------------------------------------------------------------------------
__global__ __launch_bounds__(256) void k_srprep(const float* __restrict__ Wsr,
                                                f16* __restrict__ oh) {
  const int o = blockIdx.x;
  const float* src = Wsr + (size_t)o * 2048;
  f16* dh = oh + (size_t)o * 2048;
  for (int kp = threadIdx.x; kp < 2048; kp += 256) {
    const int dd = kp >> 9, c = kp & 511;
    dh[kp] = (f16)src[c * 4 + dd];
  }
}

// ---------------------------------------------------------------------------
// Shared MFMA GEMM core: 128x128 tile, BK=32, K=512 (16 iters), 4 waves (2x2),
// fp16.  Register-prefetch of tile k+1 while MFMA on tile k hides global
// latency at the 1-2 blocks/CU occupancy these small GEMMs run at.
// ---------------------------------------------------------------------------
#define GSTR 40
struct GemmSmem { f16 A[128][GSTR]; f16 B[128][GSTR]; };

__device__ __forceinline__ void gemm_loop(GemmSmem* sm,
                                          const f16* __restrict__ aP,
                                          const f16* __restrict__ bP,
                                          int sr, int ss, int wm, int wn,
                                          int quad, int tx,
                                          floatx4 acc[4][4]) {
  half8 ra0 = *(const half8*)&aP[0];
  half8 ra1 = *(const half8*)&aP[8];
  half8 rb0 = *(const half8*)&bP[0];
  half8 rb1 = *(const half8*)&bP[8];
  for (int it = 0; it < 16; ++it) {
    *(half8*)&sm->A[sr][ss]     = ra0;
    *(half8*)&sm->A[sr][ss + 8] = ra1;
    *(half8*)&sm->B[sr][ss]     = rb0;
    *(half8*)&sm->B[sr][ss + 8] = rb1;
    __syncthreads();
    if (it + 1 < 16) {
      const f16* an = aP + (it + 1) * 32;
      const f16* bn = bP + (it + 1) * 32;
      ra0 = *(const half8*)&an[0]; ra1 = *(const half8*)&an[8];
      rb0 = *(const half8*)&bn[0]; rb1 = *(const half8*)&bn[8];
    }
    half8 ah[4];
#pragma unroll
    for (int i = 0; i < 4; ++i)
      ah[i] = *(const half8*)&sm->A[wm * 64 + i * 16 + tx][quad * 8];
#pragma unroll
    for (int j = 0; j < 4; ++j) {
      const half8 bh = *(const half8*)&sm->B[wn * 64 + j * 16 + tx][quad * 8];
#pragma unroll
      for (int i = 0; i < 4; ++i)
        acc[i][j] = __builtin_amdgcn_mfma_f32_16x16x32_f16(ah[i], bh, acc[i][j], 0, 0, 0);
    }
    __syncthreads();
  }
}

#define GEMM_PRE()                                                        \
  const int tid = threadIdx.x, lane = tid & 63, wv = tid >> 6;            \
  const int wm = wv & 1, wn = wv >> 1, quad = lane >> 4, tx = lane & 15;  \
  const int sr = tid >> 1, ss = (tid & 1) * 16;                           \
  floatx4 acc[4][4];                                                      \
  _Pragma("unroll") for (int i = 0; i < 4; ++i)                           \
  _Pragma("unroll") for (int j = 0; j < 4; ++j)                           \
      acc[i][j] = (floatx4){0.f, 0.f, 0.f, 0.f};

// ---------------------------------------------------------------------------
// K_A: SR conv as split-K GEMM.  z = b*4 + kc; chunk kc covers k' in
// [kc*512,(kc+1)*512) which is ONE shifted x-plane (dd = kc), so A is a
// plain row gather with contiguous k.  Partials -> XRp[kc].
// ---------------------------------------------------------------------------
__global__ __launch_bounds__(256) void k_srconv(const f16* __restrict__ xT,
                                                const f16* __restrict__ WsrP,
                                                float* __restrict__ XRp) {
  __shared__ GemmSmem sm;
  const int m0 = blockIdx.x * 128, n0 = blockIdx.y * 128;
  const int b = blockIdx.z >> 2, kc = blockIdx.z & 3;
  GEMM_PRE();
  int am = m0 + sr; if (am >= KNTOK) am = 0;
  const int ii = am / KH, jj = am % KH;
  const int sp = 112 * ii + 2 * jj + (kc >> 1) * FSP + (kc & 1);
  const f16* aP = xT + (size_t)b * NTOK * CDIM + (size_t)sp * CDIM + ss;
  const f16* bP = WsrP + (size_t)(n0 + sr) * 2048 + kc * 512 + ss;
  gemm_loop(&sm, aP, bP, sr, ss, wm, wn, quad, tx, acc);
  float* dst = XRp + (size_t)(kc * BATCH + b) * KNTOK * CDIM;
#pragma unroll
  for (int i = 0; i < 4; ++i)
#pragma unroll
    for (int rg = 0; rg < 4; ++rg) {
      const int m = m0 + wm * 64 + i * 16 + quad * 4 + rg;
      if (m >= KNTOK) continue;
#pragma unroll
      for (int j = 0; j < 4; ++j)
        dst[(size_t)m * CDIM + n0 + wn * 64 + j * 16 + tx] = acc[i][j][rg];
    }
}

// ---------------------------------------------------------------------------
// K_B: sum 4 split-K partials + b_sr, LayerNorm, output fp16.
// ---------------------------------------------------------------------------
__global__ __launch_bounds__(256) void k_ln(const float* __restrict__ XRp,
                                            const float* __restrict__ b_sr,
                                            const float* __restrict__ gamma,
                                            const float* __restrict__ beta,
                                            f16* __restrict__ oh) {
  const int row = blockIdx.x;
  const size_t slab = (size_t)BATCH * KNTOK * CDIM;
  const float* p = XRp + (size_t)row * CDIM;
  const int tid = threadIdx.x;
  const float v0 = p[tid] + p[tid + slab] + p[tid + 2 * slab] + p[tid + 3 * slab]
                 + b_sr[tid];
  const float v1 = p[tid + 256] + p[tid + 256 + slab] + p[tid + 256 + 2 * slab]
                 + p[tid + 256 + 3 * slab] + b_sr[tid + 256];
  float s = v0 + v1;
  float s2 = v0 * v0 + v1 * v1;
#pragma unroll
  for (int mask = 32; mask >= 1; mask >>= 1) {
    s  += __shfl_xor(s, mask, 64);
    s2 += __shfl_xor(s2, mask, 64);
  }
  __shared__ float ws[4], ws2[4];
  const int wid = tid >> 6;
  if ((tid & 63) == 0) { ws[wid] = s; ws2[wid] = s2; }
  __syncthreads();
  const float ts  = ws[0] + ws[1] + ws[2] + ws[3];
  const float ts2 = ws2[0] + ws2[1] + ws2[2] + ws2[3];
  const float mu  = ts * (1.f / CDIM);
  const float var = ts2 * (1.f / CDIM) - mu * mu;
  const float rs  = rsqrtf(var + 1e-5f);
  const size_t base = (size_t)row * CDIM;
  oh[base + tid]       = (f16)((v0 - mu) * rs * gamma[tid] + beta[tid]);
  oh[base + tid + 256] = (f16)((v1 - mu) * rs * gamma[tid + 256] + beta[tid + 256]);
}

// ---------------------------------------------------------------------------
// K_C: merged Q-projection + KV-projection (both K=512 GEMMs) in one
// dispatch (400 + 224 = 624 blocks) so the grid fills all 256 CUs.
// ---------------------------------------------------------------------------
__global__ __launch_bounds__(256) void k_qkv(const f16* __restrict__ xT,
                                             const f16* __restrict__ WqT,
                                             f16* __restrict__ Qh,
                                             const f16* __restrict__ XRh,
                                             const f16* __restrict__ WkvT,
                                             f16* __restrict__ Kh,
                                             f16* __restrict__ Vt) {
  __shared__ GemmSmem sm;
  GEMM_PRE();
  int bid = blockIdx.x;
  if (bid < 400) {            // ---- Q projection: 4b x 25m x 4n ----
    const int b = bid / 100, t = bid % 100;
    const int m0 = (t >> 2) * 128, n0 = (t & 3) * 128;
    int arow = m0 + sr; if (arow >= NTOK) arow = NTOK - 1;
    const f16* aP = xT + (size_t)b * NTOK * CDIM + (size_t)arow * CDIM + ss;
    const f16* bP = WqT + (size_t)(n0 + sr) * CDIM + ss;
    gemm_loop(&sm, aP, bP, sr, ss, wm, wn, quad, tx, acc);
    f16* qhB = Qh + (size_t)b * NTOK * CDIM;
#pragma unroll
    for (int i = 0; i < 4; ++i)
#pragma unroll
      for (int rg = 0; rg < 4; ++rg) {
        const int m = m0 + wm * 64 + i * 16 + quad * 4 + rg;
        if (m >= NTOK) continue;
#pragma unroll
        for (int j = 0; j < 4; ++j)
          qhB[(size_t)m * CDIM + n0 + wn * 64 + j * 16 + tx] = (f16)acc[i][j][rg];
      }
  } else {                    // ---- KV projection: 4b x 7m x 8n ----
    bid -= 400;
    const int b = bid / 56, w = bid % 56, nt = w / 7, mt = w % 7;
    const int m0 = mt * 128, n0 = nt * 128;
    int arow = m0 + sr; if (arow >= KNTOK) arow = KNTOK - 1;
    const f16* aP = XRh + (size_t)b * KNTOK * CDIM + (size_t)arow * CDIM + ss;
    const f16* bP = WkvT + (size_t)(n0 + sr) * CDIM + ss;
    gemm_loop(&sm, aP, bP, sr, ss, wm, wn, quad, tx, acc);
#pragma unroll
    for (int i = 0; i < 4; ++i)
#pragma unroll
      for (int rg = 0; rg < 4; ++rg) {
        const int m = m0 + wm * 64 + i * 16 + quad * 4 + rg;
        if (m >= KNTOK) continue;
#pragma unroll
        for (int j = 0; j < 4; ++j) {
          const int o2 = n0 + wn * 64 + j * 16 + tx;
          const int d = o2 >> 4, hh = (o2 >> 1) & 7;
          const float v = acc[i][j][rg];
          if (o2 & 1)
            Vt[((size_t)(b * NHEAD + hh) * HD + d) * KNTOK + m] = (f16)v;
          else
            Kh[((size_t)(b * NHEAD + hh) * KNTOK + m) * HD + d] = (f16)v;
        }
      }
  }
}

// ---------------------------------------------------------------------------
// K3: bias gather into attn-tile-interleaved layout biasT[n][jc][tx][t]
// (float4 per (row,chunk) in the attn inner loop); tail cols baked to -3e4
// so the attn loop needs no col-validity logic.
// ---------------------------------------------------------------------------
__global__ __launch_bounds__(256) void k_bias(const int* __restrict__ rel,
                                              const float* __restrict__ pos,
                                              float* __restrict__ biasT) {
  const int n = blockIdx.x;
  for (int i = threadIdx.x; i < BIAS_LD; i += 256) {
    const int jc = i >> 6, w = i & 63, txx = w >> 2, tt = w & 3;
    const int m = jc * 64 + tt * 16 + txx;
    float v = -30000.f;
    if (m < KNTOK) {
      const size_t o = ((size_t)n * NTOK + m) * 2;
      v = pos[rel[o] * 111 + rel[o + 1]];
    }
    biasT[(size_t)n * BIAS_LD + i] = v;
  }
}

// ---------------------------------------------------------------------------
// K4: MFMA flash attention, STATIC-max softmax (exponents here are tiny, so
// softmax shift-invariance lets us drop running-max/alpha entirely; l-sum is
// per-lane, reduced once at the end).  Grid (32 = b*8+h, 49 = n-tile).
// ---------------------------------------------------------------------------
#define LSTR 72
__global__ __launch_bounds__(256) void k_attn(const f16* __restrict__ Qh,
                                              const f16* __restrict__ Kh,
                                              const f16* __restrict__ Vt,
                                              const float* __restrict__ biasT,
                                              f16* __restrict__ Oh) {
  __shared__ f16 Qhs[64][LSTR], Khs[64][LSTR], Vts[64][LSTR];
  __shared__ f16 Ps[4][16][LSTR];
  const int b = blockIdx.x >> 3, h = blockIdx.x & 7;
  const int n0 = blockIdx.y * 64;
  const int tid = threadIdx.x, lane = tid & 63, wv = tid >> 6;
  const int quad = lane >> 4, tx = lane & 15;
  const int rr = tid >> 2, sg = (tid & 3) * 16;

  const f16* qhB = Qh + ((size_t)b * NTOK + n0) * CDIM + h * HD;
  const f16* khB = Kh + (size_t)(b * NHEAD + h) * KNTOK * HD;
  const f16* vtB = Vt + (size_t)(b * NHEAD + h) * HD * KNTOK;

  {
    const size_t off = (size_t)rr * CDIM + sg;
    *(half8*)&Qhs[rr][sg]     = *(const half8*)&qhB[off];
    *(half8*)&Qhs[rr][sg + 8] = *(const half8*)&qhB[off + 8];
  }

  // per-row bias base pointers (4 rows per lane)
  size_t bbase_r[4];
#pragma unroll
  for (int r = 0; r < 4; ++r) {
    const int grow = n0 + wv * 16 + quad * 4 + r;
    bbase_r[r] = (size_t)grow * BIAS_LD + tx * 4;
  }

  floatx4 acc_o[4];
#pragma unroll
  for (int t = 0; t < 4; ++t) acc_o[t] = (floatx4){0.f, 0.f, 0.f, 0.f};
  float l_part[4] = {0.f, 0.f, 0.f, 0.f};
  __syncthreads();

  for (int jc = 0; jc < 13; ++jc) {
    const int mb = jc * 64;
    const half8 z = {0, 0, 0, 0, 0, 0, 0, 0};
    {
      const int m = mb + rr;
      if (m < KNTOK) {
        const size_t off = (size_t)m * HD + sg;
        *(half8*)&Khs[rr][sg]     = *(const half8*)&khB[off];
        *(half8*)&Khs[rr][sg + 8] = *(const half8*)&khB[off + 8];
      } else {
        *(half8*)&Khs[rr][sg] = z; *(half8*)&Khs[rr][sg + 8] = z;
      }
      if (mb + sg < KNTOK) {
        const size_t voff = (size_t)rr * KNTOK + mb + sg;
        *(half8*)&Vts[rr][sg]     = *(const half8*)&vtB[voff];
        *(half8*)&Vts[rr][sg + 8] = *(const half8*)&vtB[voff + 8];
      } else {
        *(half8*)&Vts[rr][sg] = z; *(half8*)&Vts[rr][sg + 8] = z;
      }
    }
    __syncthreads();

    floatx4 sc[4];
#pragma unroll
    for (int t = 0; t < 4; ++t) sc[t] = (floatx4){0.f, 0.f, 0.f, 0.f};
#pragma unroll
    for (int ks = 0; ks < 2; ++ks) {
      const int kk = ks * 32 + quad * 8;
      const half8 aqh = *(const half8*)&Qhs[wv * 16 + tx][kk];
#pragma unroll
      for (int t = 0; t < 4; ++t) {
        const half8 bkh = *(const half8*)&Khs[t * 16 + tx][kk];
        sc[t] = __builtin_amdgcn_mfma_f32_16x16x32_f16(aqh, bkh, sc[t], 0, 0, 0);
      }
    }

    // static-max softmax: p = exp(s*scale + bias); per-lane l accumulation
#pragma unroll
    for (int r = 0; r < 4; ++r) {
      const float4 bb = *(const float4*)&biasT[bbase_r[r] + jc * 64];
      const float p0 = __expf(fmaf(sc[0][r], SCALE_ATT, bb.x));
      const float p1 = __expf(fmaf(sc[1][r], SCALE_ATT, bb.y));
      const float p2 = __expf(fmaf(sc[2][r], SCALE_ATT, bb.z));
      const float p3 = __expf(fmaf(sc[3][r], SCALE_ATT, bb.w));
      l_part[r] += (p0 + p1) + (p2 + p3);
      const int prow = quad * 4 + r;
      Ps[wv][prow][0 * 16 + tx] = (f16)p0;
      Ps[wv][prow][1 * 16 + tx] = (f16)p1;
      Ps[wv][prow][2 * 16 + tx] = (f16)p2;
      Ps[wv][prow][3 * 16 + tx] = (f16)p3;
    }

#pragma unroll
    for (int ks = 0; ks < 2; ++ks) {
      const int kk = ks * 32 + quad * 8;
      const half8 ap = *(const half8*)&Ps[wv][tx][kk];
#pragma unroll
      for (int t = 0; t < 4; ++t) {
        const half8 bv = *(const half8*)&Vts[t * 16 + tx][kk];
        acc_o[t] = __builtin_amdgcn_mfma_f32_16x16x32_f16(ap, bv, acc_o[t], 0, 0, 0);
      }
    }
    __syncthreads();
  }

#pragma unroll
  for (int r = 0; r < 4; ++r) {
    float l = l_part[r];
#pragma unroll
    for (int msk = 1; msk < 16; msk <<= 1) l += __shfl_xor(l, msk, 64);
    const float inv = 1.f / l;
    const int grow = n0 + wv * 16 + quad * 4 + r;
    const size_t base = ((size_t)b * NTOK + grow) * CDIM + h * HD;
#pragma unroll
    for (int t = 0; t < 4; ++t)
      Oh[base + t * 16 + tx] = (f16)(acc_o[t][r] * inv);
  }
}

// ---------------------------------------------------------------------------
// K5: output projection (MFMA fp16) + bp, store fp32 transposed (b, co, n).
// ---------------------------------------------------------------------------
__global__ __launch_bounds__(256) void k_outproj(const f16* __restrict__ ah_,
                                                 const f16* __restrict__ wh,
                                                 const float* __restrict__ bp,
                                                 float* __restrict__ out) {
  __shared__ GemmSmem sm;
  const int b = blockIdx.z, m0 = blockIdx.x * 128, n0 = blockIdx.y * 128;
  GEMM_PRE();
  int arow = m0 + sr; if (arow >= NTOK) arow = NTOK - 1;
  const f16* aP = ah_ + (size_t)b * NTOK * CDIM + (size_t)arow * CDIM + ss;
  const f16* bP = wh + (size_t)(n0 + sr) * CDIM + ss;
  gemm_loop(&sm, aP, bP, sr, ss, wm, wn, quad, tx, acc);
#pragma unroll
  for (int j = 0; j < 4; ++j) {
    const int co = n0 + wn * 64 + j * 16 + tx;
    const float bpv = bp[co];
    float* obase = out + ((size_t)b * CDIM + co) * NTOK;
#pragma unroll
    for (int i = 0; i < 4; ++i) {
      const int mb4 = m0 + wm * 64 + i * 16 + quad * 4;
      if (mb4 < NTOK) {
        floatx4 v = acc[i][j] + bpv;
        *(floatx4*)&obase[mb4] = v;
      }
    }
  }
}

// ---------------------------------------------------------------------------
extern "C" void kernel_launch(void* const* d_in, const int* in_sizes, int n_in,
                              void* d_out, int out_size, void* d_ws, size_t ws_size,
                              hipStream_t stream) {
  const float* x     = (const float*)d_in[0];
  const float* Wq    = (const float*)d_in[1];
  const float* Wkv   = (const float*)d_in[2];
  const float* Wsr   = (const float*)d_in[3];
  const float* b_sr  = (const float*)d_in[4];
  const float* gamma = (const float*)d_in[5];
  const float* beta  = (const float*)d_in[6];
  const float* Wp    = (const float*)d_in[7];
  const float* bp    = (const float*)d_in[8];
  const float* pos   = (const float*)d_in[9];
  const int*   rel   = (const int*)d_in[10];
  float* out = (float*)d_out;

  char* p = (char*)d_ws;
  auto alloc = [&](size_t bytes) -> void* {
    void* r = (void*)p;
    p += (bytes + 255) & ~(size_t)255;
    return r;
  };
  const size_t SZ_BNC = (size_t)BATCH * NTOK * CDIM;
  const size_t SZ_BKC = (size_t)BATCH * KNTOK * CDIM;
  const size_t SZ_KV  = (size_t)BATCH * NHEAD * KNTOK * HD;

  f16* xT    = (f16*)alloc(SZ_BNC * 2);          // aliased later as Og
  f16* WqT   = (f16*)alloc(512 * 512 * 2);
  f16* WkvT  = (f16*)alloc(1024 * 512 * 2);
  f16* WpT   = (f16*)alloc(512 * 512 * 2);
  f16* WsrP  = (f16*)alloc(512 * 2048 * 2);
  f16* Qh    = (f16*)alloc(SZ_BNC * 2);
  float* XRp = (float*)alloc(SZ_BKC * 4 * 4);    // 4 split-K partials; aliased: Kh
  f16* XRh   = (f16*)alloc(SZ_BKC * 2);
  f16* Vt    = (f16*)alloc(SZ_KV * 2);
  float* biasT = (float*)alloc((size_t)NTOK * BIAS_LD * 4);

  f16* Kh = (f16*)XRp;  // XRp dead after k_ln; Kh written in k_qkv
  f16* Og = xT;         // xT dead after k_srconv + k_qkv(q-half)

  const dim3 blk(256);
  k_tsplit<<<dim3(8, 49, BATCH), blk, 0, stream>>>(x, xT, CDIM, NTOK,
                                                   (size_t)CDIM * NTOK, (size_t)NTOK * CDIM);
  k_tsplit<<<dim3(8, 8, 1),  blk, 0, stream>>>(Wq,  WqT,  512, 512,  0, 0);
  k_tsplit<<<dim3(8, 16, 1), blk, 0, stream>>>(Wkv, WkvT, 512, 1024, 0, 0);
  k_tsplit<<<dim3(8, 8, 1),  blk, 0, stream>>>(Wp,  WpT,  512, 512,  0, 0);
  k_srprep<<<dim3(512),  blk, 0, stream>>>(Wsr, WsrP);
  k_bias  <<<dim3(NTOK), blk, 0, stream>>>(rel, pos, biasT);

  k_srconv<<<dim3(7, 4, BATCH * 4), blk, 0, stream>>>(xT, WsrP, XRp);
  k_ln    <<<dim3(BATCH * KNTOK),   blk, 0, stream>>>(XRp, b_sr, gamma, beta, XRh);
  k_qkv   <<<dim3(624),             blk, 0, stream>>>(xT, WqT, Qh, XRh, WkvT, Kh, Vt);
  k_attn  <<<dim3(BATCH * NHEAD, 49), blk, 0, stream>>>(Qh, Kh, Vt, biasT, Og);
  k_outproj<<<dim3(25, 4, BATCH),   blk, 0, stream>>>(Og, WpT, bp, out);
}

// Round 6
// 305.358 us; speedup vs baseline: 10.0505x; 1.0482x over previous
//
#include <hip/hip_runtime.h>
#include <hip/hip_bf16.h>
#include <cstdint>

constexpr int BATCH = 4;
constexpr int CDIM  = 512;
constexpr int NHEAD = 8;
constexpr int HD    = 64;
constexpr int FSP   = 56;
constexpr int NTOK  = FSP * FSP;  // 3136
constexpr int KH    = 28;
constexpr int KNTOK = KH * KH;    // 784
constexpr float SCALE_ATT = 0.125f;
constexpr int BIAS_LD = 832;      // 13 chunks * 64, tail baked to -3e4

typedef _Float16 f16;
typedef __attribute__((ext_vector_type(8))) _Float16 half8;
typedef __attribute__((ext_vector_type(4))) float  floatx4;

// ---------------------------------------------------------------------------
// Mega-prep: one dispatch for all input reshapes.
//   [0,1568)      x (b,512,3136) -> xT fp16 [b][n][c]     (64x64 transpose)
//   [1568,1632)   Wq  -> WqT  [512][512]
//   [1632,1760)   Wkv -> WkvT [1024][512]
//   [1760,1824)   Wp  -> WpT  [512][512]
//   [1824,2336)   Wsr -> WsrP [o][k'] , k' = (di*2+dj)*512 + c
//   [2336,5472)   bias gather -> biasT[n][jc][tx][t], tail = -3e4
// ---------------------------------------------------------------------------
__device__ __forceinline__ void tr64(const float* __restrict__ in,
                                     f16* __restrict__ out, int R, int C,
                                     int r0, int c0, float (*sm)[65], int tid) {
  const int rr = tid >> 2, cs = (tid & 3) * 16;
  const float* src = in + (size_t)(r0 + rr) * C + c0 + cs;
#pragma unroll
  for (int j = 0; j < 16; j += 4) *(float4*)&sm[rr][cs + j] = *(const float4*)&src[j];
  __syncthreads();
  f16* dh = out + (size_t)(c0 + rr) * R + r0 + cs;
#pragma unroll
  for (int j = 0; j < 16; ++j) dh[j] = (f16)sm[cs + j][rr];
}

__global__ __launch_bounds__(256) void k_prep(const float* __restrict__ x,
                                              const float* __restrict__ Wq,
                                              const float* __restrict__ Wkv,
                                              const float* __restrict__ Wp,
                                              const float* __restrict__ Wsr,
                                              const int* __restrict__ rel,
                                              const float* __restrict__ pos,
                                              f16* __restrict__ xT,
                                              f16* __restrict__ WqT,
                                              f16* __restrict__ WkvT,
                                              f16* __restrict__ WpT,
                                              f16* __restrict__ WsrP,
                                              float* __restrict__ biasT) {
  __shared__ float sm[64][65];
  const int tid = threadIdx.x;
  int bid = blockIdx.x;
  if (bid < 1568) {
    const int b = bid / 392, r = bid % 392;
    tr64(x + (size_t)b * CDIM * NTOK, xT + (size_t)b * NTOK * CDIM,
         CDIM, NTOK, (r % 8) * 64, (r / 8) * 64, sm, tid);
    return;
  }
  bid -= 1568;
  if (bid < 64)  { tr64(Wq,  WqT,  512, 512,  (bid % 8) * 64, (bid / 8) * 64, sm, tid); return; }
  bid -= 64;
  if (bid < 128) { tr64(Wkv, WkvT, 512, 1024, (bid % 8) * 64, (bid / 8) * 64, sm, tid); return; }
  bid -= 128;
  if (bid < 64)  { tr64(Wp,  WpT,  512, 512,  (bid % 8) * 64, (bid / 8) * 64, sm, tid); return; }
  bid -= 64;
  if (bid < 512) {
    const float* src = Wsr + (size_t)bid * 2048;
    f16* dh = WsrP + (size_t)bid * 2048;
    for (int kp = tid; kp < 2048; kp += 256) {
      const int dd = kp >> 9, c = kp & 511;
      dh[kp] = (f16)src[c * 4 + dd];
    }
    return;
  }
  bid -= 512;
  {
    const int n = bid;
    for (int i = tid; i < BIAS_LD; i += 256) {
      const int jc = i >> 6, w = i & 63, txx = w >> 2, tt = w & 3;
      const int m = jc * 64 + tt * 16 + txx;
      float v = -30000.f;
      if (m < KNTOK) {
        const size_t o = ((size_t)n * NTOK + m) * 2;
        v = pos[rel[o] * 111 + rel[o + 1]];
      }
      biasT[(size_t)n * BIAS_LD + i] = v;
    }
  }
}

// ---------------------------------------------------------------------------
// MFMA GEMM core: 64x128 tile, BK=32, K=512 (16 iters), 4 waves (2m x 2n,
// each wave 32x64), fp16, register-prefetch of tile k+1.
// LDS 15.4 KB -> many blocks/CU; small tiles keep the grid large.
// ---------------------------------------------------------------------------
#define GSTR 40
struct GemmSmem { f16 A[64][GSTR]; f16 B[128][GSTR]; };

__device__ __forceinline__ void gemm_loop64(GemmSmem* sm,
    const f16* __restrict__ aP, const f16* __restrict__ bP, bool doA,
    int sr, int ss, int wm, int wn, int quad, int tx, floatx4 acc[2][4]) {
  half8 ra0 = {0, 0, 0, 0, 0, 0, 0, 0}, ra1 = ra0;
  if (doA) { ra0 = *(const half8*)&aP[0]; ra1 = *(const half8*)&aP[8]; }
  half8 rb0 = *(const half8*)&bP[0], rb1 = *(const half8*)&bP[8];
  for (int it = 0; it < 16; ++it) {
    if (doA) { *(half8*)&sm->A[sr][ss] = ra0; *(half8*)&sm->A[sr][ss + 8] = ra1; }
    *(half8*)&sm->B[sr][ss] = rb0; *(half8*)&sm->B[sr][ss + 8] = rb1;
    __syncthreads();
    if (it + 1 < 16) {
      const f16* an = aP + (it + 1) * 32;
      const f16* bn = bP + (it + 1) * 32;
      if (doA) { ra0 = *(const half8*)&an[0]; ra1 = *(const half8*)&an[8]; }
      rb0 = *(const half8*)&bn[0]; rb1 = *(const half8*)&bn[8];
    }
    half8 ah[2];
#pragma unroll
    for (int i = 0; i < 2; ++i)
      ah[i] = *(const half8*)&sm->A[wm * 32 + i * 16 + tx][quad * 8];
#pragma unroll
    for (int j = 0; j < 4; ++j) {
      const half8 bh = *(const half8*)&sm->B[wn * 64 + j * 16 + tx][quad * 8];
#pragma unroll
      for (int i = 0; i < 2; ++i)
        acc[i][j] = __builtin_amdgcn_mfma_f32_16x16x32_f16(ah[i], bh, acc[i][j], 0, 0, 0);
    }
    __syncthreads();
  }
}

#define GEMM_PRE64()                                                      \
  const int tid = threadIdx.x, lane = tid & 63, wv = tid >> 6;            \
  const int wm = wv & 1, wn = wv >> 1, quad = lane >> 4, tx = lane & 15;  \
  const int sr = tid >> 1, ss = (tid & 1) * 16;                           \
  const bool doA = tid < 128;                                             \
  floatx4 acc[2][4];                                                      \
  _Pragma("unroll") for (int i = 0; i < 2; ++i)                           \
  _Pragma("unroll") for (int j = 0; j < 4; ++j)                           \
      acc[i][j] = (floatx4){0.f, 0.f, 0.f, 0.f};

// ---------------------------------------------------------------------------
// GEMM-A: Q projection (784 blocks) + SR-conv split-K (832 blocks) merged.
// ---------------------------------------------------------------------------
__global__ __launch_bounds__(256) void k_gemmA(const f16* __restrict__ xT,
                                               const f16* __restrict__ WqT,
                                               f16* __restrict__ Qh,
                                               const f16* __restrict__ WsrP,
                                               float* __restrict__ XRp) {
  __shared__ GemmSmem sm;
  GEMM_PRE64();
  int bid = blockIdx.x;
  if (bid < 784) {            // ---- Q projection: b4 x m49 x n4 ----
    const int b = bid / 196, r = bid % 196;
    const int m0 = (r >> 2) * 64, n0 = (r & 3) * 128;
    const f16* aP = xT + (size_t)b * NTOK * CDIM + (size_t)(m0 + sr) * CDIM + ss;
    const f16* bP = WqT + (size_t)(n0 + sr) * CDIM + ss;
    gemm_loop64(&sm, aP, bP, doA, sr, ss, wm, wn, quad, tx, acc);
    f16* qhB = Qh + (size_t)b * NTOK * CDIM;
#pragma unroll
    for (int i = 0; i < 2; ++i)
#pragma unroll
      for (int rg = 0; rg < 4; ++rg) {
        const int m = m0 + wm * 32 + i * 16 + quad * 4 + rg;
#pragma unroll
        for (int j = 0; j < 4; ++j)
          qhB[(size_t)m * CDIM + n0 + wn * 64 + j * 16 + tx] = (f16)acc[i][j][rg];
      }
  } else {                    // ---- SR conv split-K: (b,kc)16 x m13 x n4 ----
    bid -= 784;
    const int bkc = bid / 52, r = bid % 52;
    const int b = bkc >> 2, kc = bkc & 3;
    const int m0 = (r >> 2) * 64, n0 = (r & 3) * 128;
    int am = m0 + sr; if (am >= KNTOK) am = 0;
    const int ii = am / KH, jj = am % KH;
    const int sp = 112 * ii + 2 * jj + (kc >> 1) * FSP + (kc & 1);
    const f16* aP = xT + (size_t)b * NTOK * CDIM + (size_t)sp * CDIM + ss;
    const f16* bP = WsrP + (size_t)(n0 + sr) * 2048 + kc * 512 + ss;
    gemm_loop64(&sm, aP, bP, doA, sr, ss, wm, wn, quad, tx, acc);
    float* dst = XRp + (size_t)(kc * BATCH + b) * KNTOK * CDIM;
#pragma unroll
    for (int i = 0; i < 2; ++i)
#pragma unroll
      for (int rg = 0; rg < 4; ++rg) {
        const int m = m0 + wm * 32 + i * 16 + quad * 4 + rg;
        if (m >= KNTOK) continue;
#pragma unroll
        for (int j = 0; j < 4; ++j)
          dst[(size_t)m * CDIM + n0 + wn * 64 + j * 16 + tx] = acc[i][j][rg];
      }
  }
}

// ---------------------------------------------------------------------------
// LN: sum 4 split-K partials + b_sr, LayerNorm, output fp16.
// ---------------------------------------------------------------------------
__global__ __launch_bounds__(256) void k_ln(const float* __restrict__ XRp,
                                            const float* __restrict__ b_sr,
                                            const float* __restrict__ gamma,
                                            const float* __restrict__ beta,
                                            f16* __restrict__ oh) {
  const int row = blockIdx.x;
  const size_t slab = (size_t)BATCH * KNTOK * CDIM;
  const float* p = XRp + (size_t)row * CDIM;
  const int tid = threadIdx.x;
  const float v0 = p[tid] + p[tid + slab] + p[tid + 2 * slab] + p[tid + 3 * slab]
                 + b_sr[tid];
  const float v1 = p[tid + 256] + p[tid + 256 + slab] + p[tid + 256 + 2 * slab]
                 + p[tid + 256 + 3 * slab] + b_sr[tid + 256];
  float s = v0 + v1;
  float s2 = v0 * v0 + v1 * v1;
#pragma unroll
  for (int mask = 32; mask >= 1; mask >>= 1) {
    s  += __shfl_xor(s, mask, 64);
    s2 += __shfl_xor(s2, mask, 64);
  }
  __shared__ float ws[4], ws2[4];
  const int wid = tid >> 6;
  if ((tid & 63) == 0) { ws[wid] = s; ws2[wid] = s2; }
  __syncthreads();
  const float ts  = ws[0] + ws[1] + ws[2] + ws[3];
  const float ts2 = ws2[0] + ws2[1] + ws2[2] + ws2[3];
  const float mu  = ts * (1.f / CDIM);
  const float var = ts2 * (1.f / CDIM) - mu * mu;
  const float rs  = rsqrtf(var + 1e-5f);
  const size_t base = (size_t)row * CDIM;
  oh[base + tid]       = (f16)((v0 - mu) * rs * gamma[tid] + beta[tid]);
  oh[base + tid + 256] = (f16)((v1 - mu) * rs * gamma[tid + 256] + beta[tid + 256]);
}

// ---------------------------------------------------------------------------
// KV projection (416 blocks) + scatter.  K -> [b][h][m][d]; V -> [b][h][d][m].
// ---------------------------------------------------------------------------
__global__ __launch_bounds__(256) void k_kvproj(const f16* __restrict__ XRh,
                                                const f16* __restrict__ WkvT,
                                                f16* __restrict__ Kh,
                                                f16* __restrict__ Vt) {
  __shared__ GemmSmem sm;
  GEMM_PRE64();
  const int bid = blockIdx.x;
  const int b = bid / 104, r = bid % 104;
  const int m0 = (r >> 3) * 64, n0 = (r & 7) * 128;
  int arow = m0 + sr; if (arow >= KNTOK) arow = KNTOK - 1;
  const f16* aP = XRh + (size_t)b * KNTOK * CDIM + (size_t)arow * CDIM + ss;
  const f16* bP = WkvT + (size_t)(n0 + sr) * CDIM + ss;
  gemm_loop64(&sm, aP, bP, doA, sr, ss, wm, wn, quad, tx, acc);
#pragma unroll
  for (int i = 0; i < 2; ++i)
#pragma unroll
    for (int rg = 0; rg < 4; ++rg) {
      const int m = m0 + wm * 32 + i * 16 + quad * 4 + rg;
      if (m >= KNTOK) continue;
#pragma unroll
      for (int j = 0; j < 4; ++j) {
        const int o2 = n0 + wn * 64 + j * 16 + tx;
        const int d = o2 >> 4, hh = (o2 >> 1) & 7;
        const float v = acc[i][j][rg];
        if (o2 & 1)
          Vt[((size_t)(b * NHEAD + hh) * HD + d) * KNTOK + m] = (f16)v;
        else
          Kh[((size_t)(b * NHEAD + hh) * KNTOK + m) * HD + d] = (f16)v;
      }
    }
}

// ---------------------------------------------------------------------------
// Attention: MFMA, static-max softmax, register-prefetch of next K/V chunk,
// clamp-based staging (baked -3e4 bias kills tail columns).
// Grid (32 = b*8+h fast, 49 = n-tile).
// ---------------------------------------------------------------------------
#define LSTR 72
__global__ __launch_bounds__(256) void k_attn(const f16* __restrict__ Qh,
                                              const f16* __restrict__ Kh,
                                              const f16* __restrict__ Vt,
                                              const float* __restrict__ biasT,
                                              f16* __restrict__ Oh) {
  __shared__ f16 Qhs[64][LSTR], Khs[64][LSTR], Vts[64][LSTR];
  __shared__ f16 Ps[4][16][LSTR];
  const int b = blockIdx.x >> 3, h = blockIdx.x & 7;
  const int n0 = blockIdx.y * 64;
  const int tid = threadIdx.x, lane = tid & 63, wv = tid >> 6;
  const int quad = lane >> 4, tx = lane & 15;
  const int rr = tid >> 2, sg = (tid & 3) * 16;

  const f16* qhB = Qh + ((size_t)b * NTOK + n0) * CDIM + h * HD;
  const f16* khB = Kh + (size_t)(b * NHEAD + h) * KNTOK * HD;
  const f16* vtB = Vt + (size_t)(b * NHEAD + h) * HD * KNTOK;

  {  // stage Q and chunk 0 (rows/cols 0..63 all < 784)
    const size_t qoff = (size_t)rr * CDIM + sg;
    *(half8*)&Qhs[rr][sg]     = *(const half8*)&qhB[qoff];
    *(half8*)&Qhs[rr][sg + 8] = *(const half8*)&qhB[qoff + 8];
    const size_t koff = (size_t)rr * HD + sg;
    *(half8*)&Khs[rr][sg]     = *(const half8*)&khB[koff];
    *(half8*)&Khs[rr][sg + 8] = *(const half8*)&khB[koff + 8];
    const size_t voff = (size_t)rr * KNTOK + sg;
    *(half8*)&Vts[rr][sg]     = *(const half8*)&vtB[voff];
    *(half8*)&Vts[rr][sg + 8] = *(const half8*)&vtB[voff + 8];
  }

  size_t bbase_r[4];
#pragma unroll
  for (int r = 0; r < 4; ++r)
    bbase_r[r] = (size_t)(n0 + wv * 16 + quad * 4 + r) * BIAS_LD + tx * 4;

  floatx4 acc_o[4];
#pragma unroll
  for (int t = 0; t < 4; ++t) acc_o[t] = (floatx4){0.f, 0.f, 0.f, 0.f};
  float l_part[4] = {0.f, 0.f, 0.f, 0.f};
  __syncthreads();

  half8 nk0, nk1, nv0, nv1;
  for (int jc = 0; jc < 13; ++jc) {
    if (jc < 12) {  // prefetch next chunk into regs (hidden under compute)
      const int mbn = (jc + 1) * 64;
      const int km = min(mbn + rr, KNTOK - 1);
      const size_t koff = (size_t)km * HD + sg;
      nk0 = *(const half8*)&khB[koff];
      nk1 = *(const half8*)&khB[koff + 8];
      const int vc = min(mbn + sg, KNTOK - 16);
      const size_t voff = (size_t)rr * KNTOK + vc;
      nv0 = *(const half8*)&vtB[voff];
      nv1 = *(const half8*)&vtB[voff + 8];
    }

    floatx4 sc[4];
#pragma unroll
    for (int t = 0; t < 4; ++t) sc[t] = (floatx4){0.f, 0.f, 0.f, 0.f};
#pragma unroll
    for (int ks = 0; ks < 2; ++ks) {
      const int kk = ks * 32 + quad * 8;
      const half8 aqh = *(const half8*)&Qhs[wv * 16 + tx][kk];
#pragma unroll
      for (int t = 0; t < 4; ++t) {
        const half8 bkh = *(const half8*)&Khs[t * 16 + tx][kk];
        sc[t] = __builtin_amdgcn_mfma_f32_16x16x32_f16(aqh, bkh, sc[t], 0, 0, 0);
      }
    }

#pragma unroll
    for (int r = 0; r < 4; ++r) {
      const float4 bb = *(const float4*)&biasT[bbase_r[r] + jc * 64];
      const float p0 = __expf(fmaf(sc[0][r], SCALE_ATT, bb.x));
      const float p1 = __expf(fmaf(sc[1][r], SCALE_ATT, bb.y));
      const float p2 = __expf(fmaf(sc[2][r], SCALE_ATT, bb.z));
      const float p3 = __expf(fmaf(sc[3][r], SCALE_ATT, bb.w));
      l_part[r] += (p0 + p1) + (p2 + p3);
      const int prow = quad * 4 + r;
      Ps[wv][prow][0 * 16 + tx] = (f16)p0;
      Ps[wv][prow][1 * 16 + tx] = (f16)p1;
      Ps[wv][prow][2 * 16 + tx] = (f16)p2;
      Ps[wv][prow][3 * 16 + tx] = (f16)p3;
    }

#pragma unroll
    for (int ks = 0; ks < 2; ++ks) {
      const int kk = ks * 32 + quad * 8;
      const half8 ap = *(const half8*)&Ps[wv][tx][kk];
#pragma unroll
      for (int t = 0; t < 4; ++t) {
        const half8 bv = *(const half8*)&Vts[t * 16 + tx][kk];
        acc_o[t] = __builtin_amdgcn_mfma_f32_16x16x32_f16(ap, bv, acc_o[t], 0, 0, 0);
      }
    }
    __syncthreads();
    if (jc < 12) {
      *(half8*)&Khs[rr][sg]     = nk0;
      *(half8*)&Khs[rr][sg + 8] = nk1;
      *(half8*)&Vts[rr][sg]     = nv0;
      *(half8*)&Vts[rr][sg + 8] = nv1;
    }
    __syncthreads();
  }

#pragma unroll
  for (int r = 0; r < 4; ++r) {
    float l = l_part[r];
#pragma unroll
    for (int msk = 1; msk < 16; msk <<= 1) l += __shfl_xor(l, msk, 64);
    const float inv = 1.f / l;
    const int grow = n0 + wv * 16 + quad * 4 + r;
    const size_t base = ((size_t)b * NTOK + grow) * CDIM + h * HD;
#pragma unroll
    for (int t = 0; t < 4; ++t)
      Oh[base + t * 16 + tx] = (f16)(acc_o[t][r] * inv);
  }
}

// ---------------------------------------------------------------------------
// Output projection (784 blocks) + bp, store fp32 transposed (b, co, n).
// ---------------------------------------------------------------------------
__global__ __launch_bounds__(256) void k_outproj(const f16* __restrict__ Og,
                                                 const f16* __restrict__ WpT,
                                                 const float* __restrict__ bp,
                                                 float* __restrict__ out) {
  __shared__ GemmSmem sm;
  GEMM_PRE64();
  const int bid = blockIdx.x;
  const int b = bid / 196, r = bid % 196;
  const int m0 = (r >> 2) * 64, n0 = (r & 3) * 128;
  const f16* aP = Og + (size_t)b * NTOK * CDIM + (size_t)(m0 + sr) * CDIM + ss;
  const f16* bP = WpT + (size_t)(n0 + sr) * CDIM + ss;
  gemm_loop64(&sm, aP, bP, doA, sr, ss, wm, wn, quad, tx, acc);
#pragma unroll
  for (int j = 0; j < 4; ++j) {
    const int co = n0 + wn * 64 + j * 16 + tx;
    const float bpv = bp[co];
    float* obase = out + ((size_t)b * CDIM + co) * NTOK;
#pragma unroll
    for (int i = 0; i < 2; ++i) {
      const int mb4 = m0 + wm * 32 + i * 16 + quad * 4;
      floatx4 v = acc[i][j] + bpv;
      *(floatx4*)&obase[mb4] = v;
    }
  }
}

// ---------------------------------------------------------------------------
extern "C" void kernel_launch(void* const* d_in, const int* in_sizes, int n_in,
                              void* d_out, int out_size, void* d_ws, size_t ws_size,
                              hipStream_t stream) {
  const float* x     = (const float*)d_in[0];
  const float* Wq    = (const float*)d_in[1];
  const float* Wkv   = (const float*)d_in[2];
  const float* Wsr   = (const float*)d_in[3];
  const float* b_sr  = (const float*)d_in[4];
  const float* gamma = (const float*)d_in[5];
  const float* beta  = (const float*)d_in[6];
  const float* Wp    = (const float*)d_in[7];
  const float* bp    = (const float*)d_in[8];
  const float* pos   = (const float*)d_in[9];
  const int*   rel   = (const int*)d_in[10];
  float* out = (float*)d_out;

  char* p = (char*)d_ws;
  auto alloc = [&](size_t bytes) -> void* {
    void* r = (void*)p;
    p += (bytes + 255) & ~(size_t)255;
    return r;
  };
  const size_t SZ_BNC = (size_t)BATCH * NTOK * CDIM;
  const size_t SZ_BKC = (size_t)BATCH * KNTOK * CDIM;
  const size_t SZ_KV  = (size_t)BATCH * NHEAD * KNTOK * HD;

  f16* xT    = (f16*)alloc(SZ_BNC * 2);          // aliased later as Og
  f16* WqT   = (f16*)alloc(512 * 512 * 2);
  f16* WkvT  = (f16*)alloc(1024 * 512 * 2);
  f16* WpT   = (f16*)alloc(512 * 512 * 2);
  f16* WsrP  = (f16*)alloc(512 * 2048 * 2);
  f16* Qh    = (f16*)alloc(SZ_BNC * 2);
  float* XRp = (float*)alloc(SZ_BKC * 4 * 4);    // 4 split-K partials; aliased: Kh
  f16* XRh   = (f16*)alloc(SZ_BKC * 2);
  f16* Vt    = (f16*)alloc(SZ_KV * 2);
  float* biasT = (float*)alloc((size_t)NTOK * BIAS_LD * 4);

  f16* Kh = (f16*)XRp;  // XRp dead after k_ln; Kh written by k_kvproj
  f16* Og = xT;         // xT dead after k_gemmA

  const dim3 blk(256);
  k_prep   <<<dim3(5472), blk, 0, stream>>>(x, Wq, Wkv, Wp, Wsr, rel, pos,
                                            xT, WqT, WkvT, WpT, WsrP, biasT);
  k_gemmA  <<<dim3(1616), blk, 0, stream>>>(xT, WqT, Qh, WsrP, XRp);
  k_ln     <<<dim3(BATCH * KNTOK), blk, 0, stream>>>(XRp, b_sr, gamma, beta, XRh);
  k_kvproj <<<dim3(416),  blk, 0, stream>>>(XRh, WkvT, Kh, Vt);
  k_attn   <<<dim3(BATCH * NHEAD, 49), blk, 0, stream>>>(Qh, Kh, Vt, biasT, Og);
  k_outproj<<<dim3(784),  blk, 0, stream>>>(Og, WpT, bp, out);
}